// Round 1
// baseline (1420.798 us; speedup 1.0000x reference)
//
#include <hip/hip_runtime.h>
#include <hip/hip_bf16.h>

#define NN 50000
#define NE 1600000

typedef float f32x4 __attribute__((ext_vector_type(4)));
typedef short bf16x8 __attribute__((ext_vector_type(8)));

__device__ inline short f2bf(float f) {
    union { float f; unsigned u; } v; v.f = f;
    unsigned r = v.u + 0x7fffu + ((v.u >> 16) & 1u);   // RNE
    return (short)(r >> 16);
}

__device__ inline void pack8(bf16x8& d, float4 p0, float4 p1) {
    d[0]=f2bf(p0.x); d[1]=f2bf(p0.y); d[2]=f2bf(p0.z); d[3]=f2bf(p0.w);
    d[4]=f2bf(p1.x); d[5]=f2bf(p1.y); d[6]=f2bf(p1.z); d[7]=f2bf(p1.w);
}

// ---------------------------------------------------------------------------
// K0: fold weights.
// WC1[128][384]: cols 0-127 Wl, 128-255 U_i (Wl_h @ W_att[0:64]), 256-383 U_j.
// BC1[384] matching biases.
// WC2[64][160]: cols 0-31 We@W_eout, 32-159 W_v (per head h: cols 32+h*64+a).
// BC2[160] matching biases (includes b_att).
// ---------------------------------------------------------------------------
#define PREP_TOT (128*384 + 384 + 64*160 + 160)

__global__ void k_prep(const float* __restrict__ Wl, const float* __restrict__ bl,
                       const float* __restrict__ We, const float* __restrict__ be,
                       const float* __restrict__ W_att, const float* __restrict__ b_att,
                       const float* __restrict__ W_eout, const float* __restrict__ b_eout,
                       float* __restrict__ WC1, float* __restrict__ BC1,
                       float* __restrict__ WC2, float* __restrict__ BC2) {
    int id = blockIdx.x * blockDim.x + threadIdx.x;
    if (id < 128*384) {
        int k = id / 384, col = id % 384;
        float v;
        if (col < 128) v = Wl[k*128 + col];
        else {
            int role = (col - 128) >> 7;          // 0 = u_i(dst), 1 = u_j(src)
            int hc = (col - 128) & 127, h = hc >> 6, a = hc & 63;
            float s = 0.f;
            for (int c = 0; c < 64; c++) s += Wl[k*128 + h*64 + c] * W_att[(role*64 + c)*64 + a];
            v = s;
        }
        WC1[id] = v;
    } else if (id < 128*384 + 384) {
        int col = id - 128*384;
        float v;
        if (col < 128) v = bl[col];
        else {
            int role = (col - 128) >> 7;
            int hc = (col - 128) & 127, h = hc >> 6, a = hc & 63;
            float s = 0.f;
            for (int c = 0; c < 64; c++) s += bl[h*64 + c] * W_att[(role*64 + c)*64 + a];
            v = s;
        }
        BC1[col] = v;
    } else if (id < 128*384 + 384 + 64*160) {
        int id2 = id - (128*384 + 384);
        int k = id2 / 160, col = id2 % 160;
        float s = 0.f;
        if (col < 32) { for (int m = 0; m < 64; m++) s += We[k*64 + m] * W_eout[m*32 + col]; }
        else {
            int hc = col - 32, h = hc >> 6, a = hc & 63;
            for (int j = 0; j < 32; j++) s += We[k*64 + h*32 + j] * W_att[(128 + j)*64 + a];
        }
        WC2[id2] = s;
    } else if (id < PREP_TOT) {
        int col = id - (128*384 + 384 + 64*160);
        float s = 0.f;
        if (col < 32) { for (int m = 0; m < 64; m++) s += be[m] * W_eout[m*32 + col]; s += b_eout[col]; }
        else {
            int hc = col - 32, h = hc >> 6, a = hc & 63;
            for (int j = 0; j < 32; j++) s += be[h*32 + j] * W_att[(128 + j)*64 + a];
            s += b_att[a];
        }
        BC2[col] = s;
    }
}

// ---------------------------------------------------------------------------
// K1: TN[N][384] = x[N,128] @ WC1 + BC1   (bf16 MFMA, f32 out)
// Block 256 = 4 waves; 16 nodes per iter; wave w owns col-tiles 6w..6w+5.
// ---------------------------------------------------------------------------
__global__ __launch_bounds__(256) void k_node(const float* __restrict__ x,
                                              const float* __restrict__ WC1,
                                              const float* __restrict__ BC1,
                                              float* __restrict__ TN) {
    const int w = threadIdx.x >> 6, l = threadIdx.x & 63;
    const int l15 = l & 15, lhi = l >> 4;

    bf16x8 B[6][4];
    #pragma unroll
    for (int t = 0; t < 6; t++) {
        int col = (6*w + t)*16 + l15;
        #pragma unroll
        for (int ks = 0; ks < 4; ks++) {
            #pragma unroll
            for (int j = 0; j < 8; j++) {
                int k = ks*32 + lhi*8 + j;
                B[t][ks][j] = f2bf(WC1[k*384 + col]);
            }
        }
    }

    for (int nb = blockIdx.x * 16; nb < NN; nb += gridDim.x * 16) {
        int row = nb + l15;
        bf16x8 A[4];
        #pragma unroll
        for (int ks = 0; ks < 4; ks++) {
            const float* p = x + (size_t)row*128 + ks*32 + lhi*8;
            pack8(A[ks], *(const float4*)p, *(const float4*)(p + 4));
        }
        #pragma unroll
        for (int t = 0; t < 6; t++) {
            f32x4 acc = {0.f, 0.f, 0.f, 0.f};
            #pragma unroll
            for (int ks = 0; ks < 4; ks++)
                acc = __builtin_amdgcn_mfma_f32_16x16x32_bf16(A[ks], B[t][ks], acc, 0, 0, 0);
            int col = (6*w + t)*16 + l15;
            float bias = BC1[col];
            #pragma unroll
            for (int r = 0; r < 4; r++) {
                int node = nb + lhi*4 + r;
                TN[(size_t)node*384 + col] = acc[r] + bias;
            }
        }
    }
}

// ---------------------------------------------------------------------------
// K2: per 64-edge tile: C[64][160] = attr @ WC2 (MFMA). Cols 0-31 -> edge_out.
// Cols 32-159 = v+bias -> LDS; phase 2: alpha = att·leaky(v + u_i[dst]+u_j[src]),
// plus dst histogram.
// ---------------------------------------------------------------------------
__global__ __launch_bounds__(256) void k_edge(const float* __restrict__ attr,
                                              const int* __restrict__ ei,
                                              const float* __restrict__ TN,
                                              const float* __restrict__ WC2,
                                              const float* __restrict__ BC2,
                                              const float* __restrict__ att,
                                              float* __restrict__ edge_out,
                                              float* __restrict__ alpha,
                                              int* __restrict__ deg) {
    __shared__ float vlds[64 * 2 * 65];   // [(eloc*2+h)][65]
    __shared__ float att_s[128];
    const int tid = threadIdx.x;
    const int w = tid >> 6, l = tid & 63, l15 = l & 15, lhi = l >> 4;
    if (tid < 128) att_s[tid] = att[tid];

    bf16x8 B[10][2];
    #pragma unroll
    for (int t = 0; t < 10; t++) {
        int col = t*16 + l15;
        #pragma unroll
        for (int ks = 0; ks < 2; ks++) {
            #pragma unroll
            for (int j = 0; j < 8; j++) {
                int k = ks*32 + lhi*8 + j;
                B[t][ks][j] = f2bf(WC2[k*160 + col]);
            }
        }
    }

    for (int e0 = blockIdx.x * 64; e0 < NE; e0 += gridDim.x * 64) {
        int row = e0 + 16*w + l15;
        bf16x8 A[2];
        #pragma unroll
        for (int ks = 0; ks < 2; ks++) {
            const float* p = attr + (size_t)row*64 + ks*32 + lhi*8;
            pack8(A[ks], *(const float4*)p, *(const float4*)(p + 4));
        }
        #pragma unroll
        for (int t = 0; t < 10; t++) {
            f32x4 acc = {0.f, 0.f, 0.f, 0.f};
            acc = __builtin_amdgcn_mfma_f32_16x16x32_bf16(A[0], B[t][0], acc, 0, 0, 0);
            acc = __builtin_amdgcn_mfma_f32_16x16x32_bf16(A[1], B[t][1], acc, 0, 0, 0);
            int col = t*16 + l15;
            float bias = BC2[col];
            if (t < 2) {
                #pragma unroll
                for (int r = 0; r < 4; r++) {
                    int er = e0 + 16*w + lhi*4 + r;
                    edge_out[(size_t)er*32 + col] = acc[r] + bias;
                }
            } else {
                int hc = col - 32, h = hc >> 6, a = hc & 63;
                #pragma unroll
                for (int r = 0; r < 4; r++) {
                    int eloc = 16*w + lhi*4 + r;
                    vlds[(eloc*2 + h)*65 + a] = acc[r] + bias;
                }
            }
        }
        __syncthreads();
        if (tid < 128) {
            int eloc = tid >> 1, h = tid & 1;
            int e = e0 + eloc;
            int src = ei[e], dst = ei[NE + e];
            const float* ui = TN + (size_t)dst*384 + 128 + h*64;
            const float* uj = TN + (size_t)src*384 + 256 + h*64;
            const float* vv = vlds + tid*65;
            float asum = 0.f;
            #pragma unroll
            for (int q = 0; q < 16; q++) {
                float4 a4 = *(const float4*)(ui + q*4);
                float4 b4 = *(const float4*)(uj + q*4);
                const float* ap = (const float*)&a4;
                const float* bp = (const float*)&b4;
                #pragma unroll
                for (int j = 0; j < 4; j++) {
                    int a = q*4 + j;
                    float s = vv[a] + ap[j] + bp[j];
                    s = s > 0.f ? s : 0.2f * s;
                    asum += s * att_s[h*64 + a];
                }
            }
            alpha[(size_t)e*2 + h] = asum;
            if (h == 0) atomicAdd(deg + dst, 1);
        }
        __syncthreads();
    }
}

// ---------------------------------------------------------------------------
// K3: exclusive scan of deg -> offsets, cursor.  Single block, 1024 threads.
// ---------------------------------------------------------------------------
__global__ __launch_bounds__(1024) void k_scan(const int* __restrict__ deg,
                                               int* __restrict__ offsets,
                                               int* __restrict__ cursor) {
    __shared__ int buf[2][1024];
    int t = threadIdx.x;
    const int chunk = (NN + 1023) / 1024;
    int lo = t * chunk, hi = lo + chunk; if (hi > NN) hi = NN; if (lo > NN) lo = NN;
    int s = 0;
    for (int i = lo; i < hi; i++) s += deg[i];
    int pb = 0;
    buf[0][t] = s;
    __syncthreads();
    for (int d = 1; d < 1024; d <<= 1) {
        int v = buf[pb][t] + ((t >= d) ? buf[pb][t - d] : 0);
        buf[pb ^ 1][t] = v;
        pb ^= 1;
        __syncthreads();
    }
    int run = buf[pb][t] - s;     // exclusive prefix
    for (int i = lo; i < hi; i++) { offsets[i] = run; cursor[i] = run; run += deg[i]; }
    if (t == 1023) offsets[NN] = run;
}

__global__ void k_scatter(const int* __restrict__ ei, int* __restrict__ cursor,
                          int* __restrict__ perm) {
    int e = blockIdx.x * blockDim.x + threadIdx.x;
    if (e < NE) {
        int d = ei[NE + e];
        int pos = atomicAdd(cursor + d, 1);
        perm[pos] = e;
    }
}

// ---------------------------------------------------------------------------
// K4: per node (1 wave): softmax over its edges + weighted sum of xl[src]
// + node_out projection.  Block 256 = 4 nodes.
// ---------------------------------------------------------------------------
__global__ __launch_bounds__(256) void k_agg(const float* __restrict__ TN,
                                             const float* __restrict__ alpha,
                                             const int* __restrict__ perm,
                                             const int* __restrict__ offsets,
                                             const int* __restrict__ ei,
                                             const float* __restrict__ W_nout,
                                             const float* __restrict__ b_nout,
                                             float* __restrict__ node_out) {
    __shared__ float Wn[128 * 64];
    __shared__ float outs[4][128];
    const int tid = threadIdx.x, w = tid >> 6, l = tid & 63;
    for (int i = tid; i < 128 * 64; i += 256) Wn[i] = W_nout[i];
    __syncthreads();

    for (int nb = blockIdx.x * 4; nb < NN; nb += gridDim.x * 4) {
        int n = nb + w;
        int off = offsets[n], d = offsets[n + 1] - off;
        float acc0 = 0.f, acc1 = 0.f;
        if (d > 0) {
            float m0 = -1e30f, m1 = -1e30f;
            for (int j = l; j < d; j += 64) {
                int e = perm[off + j];
                float2 al = *(const float2*)(alpha + (size_t)e*2);
                m0 = fmaxf(m0, al.x); m1 = fmaxf(m1, al.y);
            }
            #pragma unroll
            for (int s = 32; s; s >>= 1) { m0 = fmaxf(m0, __shfl_xor(m0, s)); m1 = fmaxf(m1, __shfl_xor(m1, s)); }
            float s0 = 0.f, s1 = 0.f;
            for (int j = l; j < d; j += 64) {
                int e = perm[off + j];
                float2 al = *(const float2*)(alpha + (size_t)e*2);
                s0 += __expf(al.x - m0); s1 += __expf(al.y - m1);
            }
            #pragma unroll
            for (int s = 32; s; s >>= 1) { s0 += __shfl_xor(s0, s); s1 += __shfl_xor(s1, s); }
            float inv0 = 1.f / (s0 + 1e-16f), inv1 = 1.f / (s1 + 1e-16f);
            for (int j = 0; j < d; j++) {
                int e = perm[off + j];
                float2 al = *(const float2*)(alpha + (size_t)e*2);
                float w0 = __expf(al.x - m0) * inv0;
                float w1 = __expf(al.y - m1) * inv1;
                int src = ei[e];
                const float* xr = TN + (size_t)src*384;
                acc0 += w0 * xr[l];
                acc1 += w1 * xr[64 + l];
            }
        }
        outs[w][l] = acc0; outs[w][64 + l] = acc1;
        __syncthreads();
        float o = b_nout[l];
        for (int c = 0; c < 128; c++) o += outs[w][c] * Wn[c*64 + l];
        node_out[(size_t)n*64 + l] = o;
        __syncthreads();
    }
}

// ---------------------------------------------------------------------------
extern "C" void kernel_launch(void* const* d_in, const int* in_sizes, int n_in,
                              void* d_out, int out_size, void* d_ws, size_t ws_size,
                              hipStream_t stream) {
    const float* x         = (const float*)d_in[0];
    const float* edge_attr = (const float*)d_in[1];
    const int*   ei        = (const int*)  d_in[2];
    const float* Wl        = (const float*)d_in[3];
    const float* bl        = (const float*)d_in[4];
    const float* We        = (const float*)d_in[5];
    const float* be        = (const float*)d_in[6];
    const float* W_att     = (const float*)d_in[7];
    const float* b_att     = (const float*)d_in[8];
    const float* att       = (const float*)d_in[9];
    const float* W_nout    = (const float*)d_in[10];
    const float* b_nout    = (const float*)d_in[11];
    const float* W_eout    = (const float*)d_in[12];
    const float* b_eout    = (const float*)d_in[13];

    float* node_out = (float*)d_out;                 // [N,64]
    float* edge_out = node_out + (size_t)NN * 64;    // [E,32]

    float* TN    = (float*)d_ws;                     // [N,384]
    float* alpha = TN + (size_t)NN * 384;            // [E,2]
    float* WC1   = alpha + (size_t)NE * 2;           // 128*384
    float* BC1   = WC1 + 128 * 384;                  // 384
    float* WC2   = BC1 + 384;                        // 64*160
    float* BC2   = WC2 + 64 * 160;                   // 160
    int*   deg   = (int*)(BC2 + 160);                // N
    int*   offs  = deg + NN;                         // N+1
    int*   curs  = offs + NN + 1;                    // N
    int*   perm  = curs + NN;                        // E

    hipMemsetAsync(deg, 0, NN * sizeof(int), stream);

    k_prep<<<(PREP_TOT + 255) / 256, 256, 0, stream>>>(Wl, bl, We, be, W_att, b_att,
                                                       W_eout, b_eout, WC1, BC1, WC2, BC2);
    k_node<<<625, 256, 0, stream>>>(x, WC1, BC1, TN);
    k_edge<<<1250, 256, 0, stream>>>(edge_attr, ei, TN, WC2, BC2, att, edge_out, alpha, deg);
    k_scan<<<1, 1024, 0, stream>>>(deg, offs, curs);
    k_scatter<<<(NE + 255) / 256, 256, 0, stream>>>(ei, curs, perm);
    k_agg<<<1250, 256, 0, stream>>>(TN, alpha, perm, offs, ei, W_nout, b_nout, node_out);
}

// Round 2
// 753.556 us; speedup vs baseline: 1.8855x; 1.8855x over previous
//
#include <hip/hip_runtime.h>
#include <hip/hip_bf16.h>

#define NN 50000
#define NE 1600000

typedef float f32x4 __attribute__((ext_vector_type(4)));
typedef short bf16x8 __attribute__((ext_vector_type(8)));
typedef unsigned short u16;

__device__ inline short f2bf(float f) {
    union { float f; unsigned u; } v; v.f = f;
    unsigned r = v.u + 0x7fffu + ((v.u >> 16) & 1u);   // RNE
    return (short)(r >> 16);
}
__device__ inline float bf2f(u16 u) {
    union { unsigned u; float f; } v; v.u = ((unsigned)u) << 16; return v.f;
}
__device__ inline void pack8(bf16x8& d, float4 p0, float4 p1) {
    d[0]=f2bf(p0.x); d[1]=f2bf(p0.y); d[2]=f2bf(p0.z); d[3]=f2bf(p0.w);
    d[4]=f2bf(p1.x); d[5]=f2bf(p1.y); d[6]=f2bf(p1.z); d[7]=f2bf(p1.w);
}

// ---------------------------------------------------------------------------
// K0: fold weights.
// WC1[128][384]: cols 0-127 Wl, 128-255 U_i (Wl_h @ W_att[0:64]), 256-383 U_j.
// WC2[64][160]: cols 0-31 We@W_eout, 32-159 W_v.
// ---------------------------------------------------------------------------
#define PREP_TOT (128*384 + 384 + 64*160 + 160)

__global__ void k_prep(const float* __restrict__ Wl, const float* __restrict__ bl,
                       const float* __restrict__ We, const float* __restrict__ be,
                       const float* __restrict__ W_att, const float* __restrict__ b_att,
                       const float* __restrict__ W_eout, const float* __restrict__ b_eout,
                       float* __restrict__ WC1, float* __restrict__ BC1,
                       float* __restrict__ WC2, float* __restrict__ BC2) {
    int id = blockIdx.x * blockDim.x + threadIdx.x;
    if (id < 128*384) {
        int k = id / 384, col = id % 384;
        float v;
        if (col < 128) v = Wl[k*128 + col];
        else {
            int role = (col - 128) >> 7;          // 0 = u_i(dst), 1 = u_j(src)
            int hc = (col - 128) & 127, h = hc >> 6, a = hc & 63;
            float s = 0.f;
            for (int c = 0; c < 64; c++) s += Wl[k*128 + h*64 + c] * W_att[(role*64 + c)*64 + a];
            v = s;
        }
        WC1[id] = v;
    } else if (id < 128*384 + 384) {
        int col = id - 128*384;
        float v;
        if (col < 128) v = bl[col];
        else {
            int role = (col - 128) >> 7;
            int hc = (col - 128) & 127, h = hc >> 6, a = hc & 63;
            float s = 0.f;
            for (int c = 0; c < 64; c++) s += bl[h*64 + c] * W_att[(role*64 + c)*64 + a];
            v = s;
        }
        BC1[col] = v;
    } else if (id < 128*384 + 384 + 64*160) {
        int id2 = id - (128*384 + 384);
        int k = id2 / 160, col = id2 % 160;
        float s = 0.f;
        if (col < 32) { for (int m = 0; m < 64; m++) s += We[k*64 + m] * W_eout[m*32 + col]; }
        else {
            int hc = col - 32, h = hc >> 6, a = hc & 63;
            for (int j = 0; j < 32; j++) s += We[k*64 + h*32 + j] * W_att[(128 + j)*64 + a];
        }
        WC2[id2] = s;
    } else if (id < PREP_TOT) {
        int col = id - (128*384 + 384 + 64*160);
        float s = 0.f;
        if (col < 32) { for (int m = 0; m < 64; m++) s += be[m] * W_eout[m*32 + col]; s += b_eout[col]; }
        else {
            int hc = col - 32, h = hc >> 6, a = hc & 63;
            for (int j = 0; j < 32; j++) s += be[h*32 + j] * W_att[(128 + j)*64 + a];
            s += b_att[a];
        }
        BC2[col] = s;
    }
}

// ---------------------------------------------------------------------------
// K1: node transform -> XL[N,128] bf16 (xl) and UU[N,256] bf16 (u_i|u_j).
// ---------------------------------------------------------------------------
__global__ __launch_bounds__(256) void k_node(const float* __restrict__ x,
                                              const float* __restrict__ WC1,
                                              const float* __restrict__ BC1,
                                              u16* __restrict__ XL,
                                              u16* __restrict__ UU) {
    const int w = threadIdx.x >> 6, l = threadIdx.x & 63;
    const int l15 = l & 15, lhi = l >> 4;

    bf16x8 B[6][4];
    #pragma unroll
    for (int t = 0; t < 6; t++) {
        int col = (6*w + t)*16 + l15;
        #pragma unroll
        for (int ks = 0; ks < 4; ks++) {
            #pragma unroll
            for (int j = 0; j < 8; j++) {
                int k = ks*32 + lhi*8 + j;
                B[t][ks][j] = f2bf(WC1[k*384 + col]);
            }
        }
    }

    for (int nb = blockIdx.x * 16; nb < NN; nb += gridDim.x * 16) {
        int row = nb + l15;
        bf16x8 A[4];
        #pragma unroll
        for (int ks = 0; ks < 4; ks++) {
            const float* p = x + (size_t)row*128 + ks*32 + lhi*8;
            pack8(A[ks], *(const float4*)p, *(const float4*)(p + 4));
        }
        #pragma unroll
        for (int t = 0; t < 6; t++) {
            f32x4 acc = {0.f, 0.f, 0.f, 0.f};
            #pragma unroll
            for (int ks = 0; ks < 4; ks++)
                acc = __builtin_amdgcn_mfma_f32_16x16x32_bf16(A[ks], B[t][ks], acc, 0, 0, 0);
            int col = (6*w + t)*16 + l15;
            float bias = BC1[col];
            #pragma unroll
            for (int r = 0; r < 4; r++) {
                int node = nb + lhi*4 + r;
                float v = acc[r] + bias;
                if (col < 128) XL[(size_t)node*128 + col] = (u16)f2bf(v);
                else           UU[(size_t)node*256 + (col - 128)] = (u16)f2bf(v);
            }
        }
    }
}

// ---------------------------------------------------------------------------
// K2: per 64-edge tile: C[64][160] = attr @ WC2 (MFMA). Cols 0-31 -> edge_out.
// Cols 32-159 = v+bias -> LDS; phase 2: alpha = att . leaky(v + u_i + u_j).
// ---------------------------------------------------------------------------
__global__ __launch_bounds__(256) void k_edge(const float* __restrict__ attr,
                                              const int* __restrict__ ei,
                                              const u16* __restrict__ UU,
                                              const float* __restrict__ WC2,
                                              const float* __restrict__ BC2,
                                              const float* __restrict__ att,
                                              float* __restrict__ edge_out,
                                              float* __restrict__ alpha,
                                              int* __restrict__ deg) {
    __shared__ float vlds[64 * 2 * 65];   // [(eloc*2+h)][65]
    __shared__ float att_s[128];
    const int tid = threadIdx.x;
    const int w = tid >> 6, l = tid & 63, l15 = l & 15, lhi = l >> 4;
    if (tid < 128) att_s[tid] = att[tid];

    bf16x8 B[10][2];
    #pragma unroll
    for (int t = 0; t < 10; t++) {
        int col = t*16 + l15;
        #pragma unroll
        for (int ks = 0; ks < 2; ks++) {
            #pragma unroll
            for (int j = 0; j < 8; j++) {
                int k = ks*32 + lhi*8 + j;
                B[t][ks][j] = f2bf(WC2[k*160 + col]);
            }
        }
    }

    for (int e0 = blockIdx.x * 64; e0 < NE; e0 += gridDim.x * 64) {
        int row = e0 + 16*w + l15;
        bf16x8 A[2];
        #pragma unroll
        for (int ks = 0; ks < 2; ks++) {
            const float* p = attr + (size_t)row*64 + ks*32 + lhi*8;
            pack8(A[ks], *(const float4*)p, *(const float4*)(p + 4));
        }
        #pragma unroll
        for (int t = 0; t < 10; t++) {
            f32x4 acc = {0.f, 0.f, 0.f, 0.f};
            acc = __builtin_amdgcn_mfma_f32_16x16x32_bf16(A[0], B[t][0], acc, 0, 0, 0);
            acc = __builtin_amdgcn_mfma_f32_16x16x32_bf16(A[1], B[t][1], acc, 0, 0, 0);
            int col = t*16 + l15;
            float bias = BC2[col];
            if (t < 2) {
                #pragma unroll
                for (int r = 0; r < 4; r++) {
                    int er = e0 + 16*w + lhi*4 + r;
                    edge_out[(size_t)er*32 + col] = acc[r] + bias;
                }
            } else {
                int hc = col - 32, h = hc >> 6, a = hc & 63;
                #pragma unroll
                for (int r = 0; r < 4; r++) {
                    int eloc = 16*w + lhi*4 + r;
                    vlds[(eloc*2 + h)*65 + a] = acc[r] + bias;
                }
            }
        }
        __syncthreads();
        if (tid < 128) {
            int eloc = tid >> 1, h = tid & 1;
            int e = e0 + eloc;
            int src = ei[e], dst = ei[NE + e];
            const u16* ui = UU + (size_t)dst*256 + h*64;
            const u16* uj = UU + (size_t)src*256 + 128 + h*64;
            const float* vv = vlds + tid*65;
            const float* aa = att_s + h*64;
            float asum = 0.f;
            #pragma unroll
            for (int q = 0; q < 8; q++) {
                bf16x8 au = *(const bf16x8*)(ui + q*8);
                bf16x8 bu = *(const bf16x8*)(uj + q*8);
                #pragma unroll
                for (int j = 0; j < 8; j++) {
                    int a = q*8 + j;
                    float s = vv[a] + bf2f((u16)au[j]) + bf2f((u16)bu[j]);
                    s = s > 0.f ? s : 0.2f * s;
                    asum += s * aa[a];
                }
            }
            alpha[(size_t)e*2 + h] = asum;
            if (h == 0) atomicAdd(deg + dst, 1);
        }
        __syncthreads();
    }
}

// ---------------------------------------------------------------------------
// K3: exclusive scan of deg -> offsets, cursor.  Single block, 1024 threads.
// ---------------------------------------------------------------------------
__global__ __launch_bounds__(1024) void k_scan(const int* __restrict__ deg,
                                               int* __restrict__ offsets,
                                               int* __restrict__ cursor) {
    __shared__ int buf[2][1024];
    int t = threadIdx.x;
    const int chunk = (NN + 1023) / 1024;
    int lo = t * chunk, hi = lo + chunk; if (hi > NN) hi = NN; if (lo > NN) lo = NN;
    int s = 0;
    for (int i = lo; i < hi; i++) s += deg[i];
    int pb = 0;
    buf[0][t] = s;
    __syncthreads();
    for (int d = 1; d < 1024; d <<= 1) {
        int v = buf[pb][t] + ((t >= d) ? buf[pb][t - d] : 0);
        buf[pb ^ 1][t] = v;
        pb ^= 1;
        __syncthreads();
    }
    int run = buf[pb][t] - s;     // exclusive prefix
    for (int i = lo; i < hi; i++) { offsets[i] = run; cursor[i] = run; run += deg[i]; }
    if (t == 1023) offsets[NN] = run;
}

// K3b: CSR scatter — de-indirected payload: src id + alpha pair per slot.
__global__ void k_scatter(const int* __restrict__ ei, const float* __restrict__ alpha,
                          int* __restrict__ cursor,
                          int* __restrict__ src_s, float2* __restrict__ aw) {
    int e = blockIdx.x * blockDim.x + threadIdx.x;
    if (e < NE) {
        int d = ei[NE + e];
        int pos = atomicAdd(cursor + d, 1);
        src_s[pos] = ei[e];
        aw[pos] = *(const float2*)(alpha + (size_t)e*2);
    }
}

// ---------------------------------------------------------------------------
// K4: 1 wave per node: online softmax over contiguous aw, then weighted
// gather-sum of XL rows (2 features per lane).  No LDS, no syncthreads.
// ---------------------------------------------------------------------------
__global__ __launch_bounds__(256) void k_agg(const u16* __restrict__ XL,
                                             const float2* __restrict__ aw,
                                             const int* __restrict__ src_s,
                                             const int* __restrict__ offsets,
                                             u16* __restrict__ out128) {
    const int w = threadIdx.x >> 6, l = threadIdx.x & 63;
    for (int n = blockIdx.x * 4 + w; n < NN; n += gridDim.x * 4) {
        int off = offsets[n], d = offsets[n + 1] - off;
        float acc0 = 0.f, acc1 = 0.f;
        if (d > 0) {
            // online max + sumexp, contiguous reads
            float m0 = -1e30f, m1 = -1e30f, s0 = 0.f, s1 = 0.f;
            for (int j0 = 0; j0 < d; j0 += 64) {
                int j = j0 + l;
                float a0 = -1e30f, a1 = -1e30f;
                if (j < d) { float2 a = aw[off + j]; a0 = a.x; a1 = a.y; }
                float c0 = a0, c1 = a1;
                #pragma unroll
                for (int sh = 32; sh; sh >>= 1) { c0 = fmaxf(c0, __shfl_xor(c0, sh)); c1 = fmaxf(c1, __shfl_xor(c1, sh)); }
                float nm0 = fmaxf(m0, c0), nm1 = fmaxf(m1, c1);
                float e0 = (j < d) ? __expf(a0 - nm0) : 0.f;
                float e1 = (j < d) ? __expf(a1 - nm1) : 0.f;
                #pragma unroll
                for (int sh = 32; sh; sh >>= 1) { e0 += __shfl_xor(e0, sh); e1 += __shfl_xor(e1, sh); }
                s0 = s0 * __expf(m0 - nm0) + e0;
                s1 = s1 * __expf(m1 - nm1) + e1;
                m0 = nm0; m1 = nm1;
            }
            float inv0 = 1.f / (s0 + 1e-16f), inv1 = 1.f / (s1 + 1e-16f);

            // weighted gather-sum; lane l covers features 2l, 2l+1
            for (int j0 = 0; j0 < d; j0 += 64) {
                int j = j0 + l;
                int sj = 0; float w0 = 0.f, w1 = 0.f;
                if (j < d) {
                    sj = src_s[off + j];
                    float2 a = aw[off + j];
                    w0 = __expf(a.x - m0) * inv0;
                    w1 = __expf(a.y - m1) * inv1;
                }
                int cnt = min(64, d - j0);
                #pragma unroll 4
                for (int jj = 0; jj < cnt; jj++) {
                    int s = __shfl(sj, jj);
                    float W0 = __shfl(w0, jj), W1 = __shfl(w1, jj);
                    unsigned v = *(const unsigned*)(XL + (size_t)s*128 + 2*l);
                    union { unsigned u; float f; } f0, f1;
                    f0.u = v << 16; f1.u = v & 0xffff0000u;
                    float Wm = (l < 32) ? W0 : W1;
                    acc0 += Wm * f0.f; acc1 += Wm * f1.f;
                }
            }
        }
        unsigned pk = ((unsigned)(u16)f2bf(acc0)) | (((unsigned)(u16)f2bf(acc1)) << 16);
        *(unsigned*)(out128 + (size_t)n*128 + 2*l) = pk;
    }
}

// ---------------------------------------------------------------------------
// K5: node_out[N,64] = out128[N,128](bf16) @ W_nout + b_nout   (MFMA)
// ---------------------------------------------------------------------------
__global__ __launch_bounds__(256) void k_proj(const u16* __restrict__ out128,
                                              const float* __restrict__ Wn,
                                              const float* __restrict__ bn,
                                              float* __restrict__ node_out) {
    const int w = threadIdx.x >> 6, l = threadIdx.x & 63;
    const int l15 = l & 15, lhi = l >> 4;

    bf16x8 B[4][4];
    #pragma unroll
    for (int t = 0; t < 4; t++) {
        int col = t*16 + l15;
        #pragma unroll
        for (int ks = 0; ks < 4; ks++) {
            #pragma unroll
            for (int j = 0; j < 8; j++) {
                int k = ks*32 + lhi*8 + j;
                B[t][ks][j] = f2bf(Wn[k*64 + col]);
            }
        }
    }

    int nb = blockIdx.x * 64;
    int row = nb + 16*w + l15;
    int rowc = row < NN ? row : NN - 1;
    bf16x8 A[4];
    #pragma unroll
    for (int ks = 0; ks < 4; ks++)
        A[ks] = *(const bf16x8*)(out128 + (size_t)rowc*128 + ks*32 + lhi*8);
    #pragma unroll
    for (int t = 0; t < 4; t++) {
        f32x4 acc = {0.f, 0.f, 0.f, 0.f};
        #pragma unroll
        for (int ks = 0; ks < 4; ks++)
            acc = __builtin_amdgcn_mfma_f32_16x16x32_bf16(A[ks], B[t][ks], acc, 0, 0, 0);
        int col = t*16 + l15;
        float bias = bn[col];
        #pragma unroll
        for (int r = 0; r < 4; r++) {
            int node = nb + 16*w + lhi*4 + r;
            if (node < NN) node_out[(size_t)node*64 + col] = acc[r] + bias;
        }
    }
}

// ---------------------------------------------------------------------------
extern "C" void kernel_launch(void* const* d_in, const int* in_sizes, int n_in,
                              void* d_out, int out_size, void* d_ws, size_t ws_size,
                              hipStream_t stream) {
    const float* x         = (const float*)d_in[0];
    const float* edge_attr = (const float*)d_in[1];
    const int*   ei        = (const int*)  d_in[2];
    const float* Wl        = (const float*)d_in[3];
    const float* bl        = (const float*)d_in[4];
    const float* We        = (const float*)d_in[5];
    const float* be        = (const float*)d_in[6];
    const float* W_att     = (const float*)d_in[7];
    const float* b_att     = (const float*)d_in[8];
    const float* att       = (const float*)d_in[9];
    const float* W_nout    = (const float*)d_in[10];
    const float* b_nout    = (const float*)d_in[11];
    const float* W_eout    = (const float*)d_in[12];
    const float* b_eout    = (const float*)d_in[13];

    float* node_out = (float*)d_out;                 // [N,64]
    float* edge_out = node_out + (size_t)NN * 64;    // [E,32]

    char* p = (char*)d_ws;
    u16* XL      = (u16*)p;            p += (size_t)NN * 128 * 2;   // bf16 [N,128]
    u16* UU      = (u16*)p;            p += (size_t)NN * 256 * 2;   // bf16 [N,256]
    u16* out128  = (u16*)p;            p += (size_t)NN * 128 * 2;   // bf16 [N,128]
    float* alpha = (float*)p;          p += (size_t)NE * 2 * 4;     // [E,2]
    float2* aw   = (float2*)p;         p += (size_t)NE * 2 * 4;     // CSR alpha
    float* WC1   = (float*)p;          p += 128 * 384 * 4;
    float* BC1   = (float*)p;          p += 384 * 4;
    float* WC2   = (float*)p;          p += 64 * 160 * 4;
    float* BC2   = (float*)p;          p += 160 * 4;
    int*   src_s = (int*)p;            p += (size_t)NE * 4;         // CSR src ids
    int*   deg   = (int*)p;            p += NN * 4;
    int*   offs  = (int*)p;            p += (NN + 1) * 4;
    int*   curs  = (int*)p;            p += NN * 4;

    hipMemsetAsync(deg, 0, NN * sizeof(int), stream);

    k_prep<<<(PREP_TOT + 255) / 256, 256, 0, stream>>>(Wl, bl, We, be, W_att, b_att,
                                                       W_eout, b_eout, WC1, BC1, WC2, BC2);
    k_node<<<625, 256, 0, stream>>>(x, WC1, BC1, XL, UU);
    k_edge<<<1250, 256, 0, stream>>>(edge_attr, ei, UU, WC2, BC2, att, edge_out, alpha, deg);
    k_scan<<<1, 1024, 0, stream>>>(deg, offs, curs);
    k_scatter<<<(NE + 255) / 256, 256, 0, stream>>>(ei, alpha, curs, src_s, aw);
    k_agg<<<2048, 256, 0, stream>>>(XL, aw, src_s, offs, out128);
    k_proj<<<(NN + 63) / 64, 256, 0, stream>>>(out128, W_nout, b_nout, node_out);
}

// Round 3
// 690.929 us; speedup vs baseline: 2.0564x; 1.0906x over previous
//
#include <hip/hip_runtime.h>
#include <hip/hip_bf16.h>

#define NN 50000
#define NE 1600000

typedef float f32x4 __attribute__((ext_vector_type(4)));
typedef short bf16x8 __attribute__((ext_vector_type(8)));
typedef unsigned short u16;

__device__ inline short f2bf(float f) {
    union { float f; unsigned u; } v; v.f = f;
    unsigned r = v.u + 0x7fffu + ((v.u >> 16) & 1u);   // RNE
    return (short)(r >> 16);
}
__device__ inline float bf2f(u16 u) {
    union { unsigned u; float f; } v; v.u = ((unsigned)u) << 16; return v.f;
}
__device__ inline void pack8(bf16x8& d, float4 p0, float4 p1) {
    d[0]=f2bf(p0.x); d[1]=f2bf(p0.y); d[2]=f2bf(p0.z); d[3]=f2bf(p0.w);
    d[4]=f2bf(p1.x); d[5]=f2bf(p1.y); d[6]=f2bf(p1.z); d[7]=f2bf(p1.w);
}

// ---------------------------------------------------------------------------
// K0: fold weights.
// WC1[128][384]: cols 0-127 Wl, 128-255 U_i (Wl_h @ W_att[0:64]), 256-383 U_j.
// WC2[64][160]: cols 0-31 We@W_eout, 32-159 W_v.
// ---------------------------------------------------------------------------
#define PREP_TOT (128*384 + 384 + 64*160 + 160)

__global__ void k_prep(const float* __restrict__ Wl, const float* __restrict__ bl,
                       const float* __restrict__ We, const float* __restrict__ be,
                       const float* __restrict__ W_att, const float* __restrict__ b_att,
                       const float* __restrict__ W_eout, const float* __restrict__ b_eout,
                       float* __restrict__ WC1, float* __restrict__ BC1,
                       float* __restrict__ WC2, float* __restrict__ BC2) {
    int id = blockIdx.x * blockDim.x + threadIdx.x;
    if (id < 128*384) {
        int k = id / 384, col = id % 384;
        float v;
        if (col < 128) v = Wl[k*128 + col];
        else {
            int role = (col - 128) >> 7;          // 0 = u_i(dst), 1 = u_j(src)
            int hc = (col - 128) & 127, h = hc >> 6, a = hc & 63;
            float s = 0.f;
            for (int c = 0; c < 64; c++) s += Wl[k*128 + h*64 + c] * W_att[(role*64 + c)*64 + a];
            v = s;
        }
        WC1[id] = v;
    } else if (id < 128*384 + 384) {
        int col = id - 128*384;
        float v;
        if (col < 128) v = bl[col];
        else {
            int role = (col - 128) >> 7;
            int hc = (col - 128) & 127, h = hc >> 6, a = hc & 63;
            float s = 0.f;
            for (int c = 0; c < 64; c++) s += bl[h*64 + c] * W_att[(role*64 + c)*64 + a];
            v = s;
        }
        BC1[col] = v;
    } else if (id < 128*384 + 384 + 64*160) {
        int id2 = id - (128*384 + 384);
        int k = id2 / 160, col = id2 % 160;
        float s = 0.f;
        if (col < 32) { for (int m = 0; m < 64; m++) s += We[k*64 + m] * W_eout[m*32 + col]; }
        else {
            int hc = col - 32, h = hc >> 6, a = hc & 63;
            for (int j = 0; j < 32; j++) s += We[k*64 + h*32 + j] * W_att[(128 + j)*64 + a];
        }
        WC2[id2] = s;
    } else if (id < PREP_TOT) {
        int col = id - (128*384 + 384 + 64*160);
        float s = 0.f;
        if (col < 32) { for (int m = 0; m < 64; m++) s += be[m] * W_eout[m*32 + col]; s += b_eout[col]; }
        else {
            int hc = col - 32, h = hc >> 6, a = hc & 63;
            for (int j = 0; j < 32; j++) s += be[h*32 + j] * W_att[(128 + j)*64 + a];
            s += b_att[a];
        }
        BC2[col] = s;
    }
}

// K0b: pre-pack WC2 into per-lane bf16 MFMA B-fragments.
// WC2b[((t*2+ks)*64 + l)*8 + j] = bf16(WC2[(ks*32+(l>>4)*8+j)*160 + t*16+(l&15)])
__global__ void k_prep2(const float* __restrict__ WC2, u16* __restrict__ WC2b) {
    int id = blockIdx.x * blockDim.x + threadIdx.x;
    if (id < 10240) {
        int j = id & 7, l = (id >> 3) & 63, ks = (id >> 9) & 1, t = id >> 10;
        int col = t*16 + (l & 15);
        int k = ks*32 + (l >> 4)*8 + j;
        WC2b[id] = (u16)f2bf(WC2[k*160 + col]);
    }
}

// ---------------------------------------------------------------------------
// K1: node transform -> XL[N,128] bf16 (xl) and UU[N,256] bf16 (u_i|u_j).
// ---------------------------------------------------------------------------
__global__ __launch_bounds__(256) void k_node(const float* __restrict__ x,
                                              const float* __restrict__ WC1,
                                              const float* __restrict__ BC1,
                                              u16* __restrict__ XL,
                                              u16* __restrict__ UU) {
    const int w = threadIdx.x >> 6, l = threadIdx.x & 63;
    const int l15 = l & 15, lhi = l >> 4;

    bf16x8 B[6][4];
    #pragma unroll
    for (int t = 0; t < 6; t++) {
        int col = (6*w + t)*16 + l15;
        #pragma unroll
        for (int ks = 0; ks < 4; ks++) {
            #pragma unroll
            for (int j = 0; j < 8; j++) {
                int k = ks*32 + lhi*8 + j;
                B[t][ks][j] = f2bf(WC1[k*384 + col]);
            }
        }
    }

    for (int nb = blockIdx.x * 16; nb < NN; nb += gridDim.x * 16) {
        int row = nb + l15;
        bf16x8 A[4];
        #pragma unroll
        for (int ks = 0; ks < 4; ks++) {
            const float* p = x + (size_t)row*128 + ks*32 + lhi*8;
            pack8(A[ks], *(const float4*)p, *(const float4*)(p + 4));
        }
        #pragma unroll
        for (int t = 0; t < 6; t++) {
            f32x4 acc = {0.f, 0.f, 0.f, 0.f};
            #pragma unroll
            for (int ks = 0; ks < 4; ks++)
                acc = __builtin_amdgcn_mfma_f32_16x16x32_bf16(A[ks], B[t][ks], acc, 0, 0, 0);
            int col = (6*w + t)*16 + l15;
            float bias = BC1[col];
            #pragma unroll
            for (int r = 0; r < 4; r++) {
                int node = nb + lhi*4 + r;
                float v = acc[r] + bias;
                if (col < 128) XL[(size_t)node*128 + col] = (u16)f2bf(v);
                else           UU[(size_t)node*256 + (col - 128)] = (u16)f2bf(v);
            }
        }
    }
}

// ---------------------------------------------------------------------------
// K2: wave-autonomous edge kernel. Each wave: 16 edges/iter.
//   Phase 1: C[16][160] = attr @ WC2 (MFMA); t<2 -> edge_out, t>=2 -> private LDS.
//   Phase 2: all 64 lanes = (edge, head, half); 32-value reduction each;
//            shfl_xor(1) combines halves. No __syncthreads in the loop.
// LDS padding: per-edge stride 133 f32, head 66, half 33 (odd offsets mod 32).
// ---------------------------------------------------------------------------
__global__ __launch_bounds__(256) void k_edge(const float* __restrict__ attr,
                                              const int* __restrict__ ei,
                                              const u16* __restrict__ UU,
                                              const u16* __restrict__ WC2b,
                                              const float* __restrict__ BC2,
                                              const float* __restrict__ att,
                                              float* __restrict__ edge_out,
                                              float* __restrict__ alpha,
                                              int* __restrict__ deg) {
    __shared__ float vlds[4][16 * 133];
    __shared__ float att_p[131];
    const int tid = threadIdx.x;
    const int w = tid >> 6, l = tid & 63, l15 = l & 15, lhi = l >> 4;

    if (tid < 128) {
        int h = tid >> 6, rem = tid & 63, half = rem >> 5, q = rem & 31;
        att_p[h*66 + half*33 + q] = att[tid];
    }

    bf16x8 B[10][2];
    #pragma unroll
    for (int t = 0; t < 10; t++)
        #pragma unroll
        for (int ks = 0; ks < 2; ks++)
            B[t][ks] = *(const bf16x8*)(WC2b + (size_t)((t*2 + ks)*64 + l)*8);

    float* vw = vlds[w];
    // phase-2 lane roles
    const int e_loc = l >> 2, h2 = (l >> 1) & 1, half2 = l & 1;
    const float* vbase = vw + e_loc*133 + h2*66 + half2*33;
    const float* abase = att_p + h2*66 + half2*33;

    __syncthreads();   // att_p ready (once)

    for (int e0 = (blockIdx.x*4 + w)*16; e0 < NE; e0 += gridDim.x*64) {
        int row = e0 + l15;
        bf16x8 A[2];
        #pragma unroll
        for (int ks = 0; ks < 2; ks++) {
            const float* p = attr + (size_t)row*64 + ks*32 + lhi*8;
            pack8(A[ks], *(const float4*)p, *(const float4*)(p + 4));
        }
        #pragma unroll
        for (int t = 0; t < 10; t++) {
            f32x4 acc = {0.f, 0.f, 0.f, 0.f};
            acc = __builtin_amdgcn_mfma_f32_16x16x32_bf16(A[0], B[t][0], acc, 0, 0, 0);
            acc = __builtin_amdgcn_mfma_f32_16x16x32_bf16(A[1], B[t][1], acc, 0, 0, 0);
            int col = t*16 + l15;
            float bias = BC2[col];
            if (t < 2) {
                #pragma unroll
                for (int r = 0; r < 4; r++) {
                    int er = e0 + lhi*4 + r;
                    edge_out[(size_t)er*32 + col] = acc[r] + bias;
                }
            } else {
                int hc = col - 32, h = hc >> 6, a = hc & 63;
                int idx = h*66 + (a >> 5)*33 + (a & 31);
                #pragma unroll
                for (int r = 0; r < 4; r++)
                    vw[(lhi*4 + r)*133 + idx] = acc[r] + bias;
            }
        }

        // ---- phase 2 (same wave; lgkmcnt ordering only) ----
        int e = e0 + e_loc;
        int src = ei[e], dst = ei[NE + e];
        const u16* up = UU + (size_t)dst*256 + h2*64 + half2*32;
        const u16* vp = UU + (size_t)src*256 + 128 + h2*64 + half2*32;
        float asum = 0.f;
        #pragma unroll
        for (int q4 = 0; q4 < 4; q4++) {
            bf16x8 au = *(const bf16x8*)(up + q4*8);
            bf16x8 bu = *(const bf16x8*)(vp + q4*8);
            #pragma unroll
            for (int j = 0; j < 8; j++) {
                int q = q4*8 + j;
                float s = vbase[q] + bf2f((u16)au[j]) + bf2f((u16)bu[j]);
                s = s > 0.f ? s : 0.2f * s;
                asum += s * abase[q];
            }
        }
        asum += __shfl_xor(asum, 1);
        if (half2 == 0) alpha[(size_t)e*2 + h2] = asum;
        if ((l & 3) == 0) atomicAdd(deg + dst, 1);
    }
}

// ---------------------------------------------------------------------------
// K3: exclusive scan of deg -> offsets, cursor.  Single block, 1024 threads.
// ---------------------------------------------------------------------------
__global__ __launch_bounds__(1024) void k_scan(const int* __restrict__ deg,
                                               int* __restrict__ offsets,
                                               int* __restrict__ cursor) {
    __shared__ int buf[2][1024];
    int t = threadIdx.x;
    const int chunk = (NN + 1023) / 1024;
    int lo = t * chunk, hi = lo + chunk; if (hi > NN) hi = NN; if (lo > NN) lo = NN;
    int s = 0;
    for (int i = lo; i < hi; i++) s += deg[i];
    int pb = 0;
    buf[0][t] = s;
    __syncthreads();
    for (int d = 1; d < 1024; d <<= 1) {
        int v = buf[pb][t] + ((t >= d) ? buf[pb][t - d] : 0);
        buf[pb ^ 1][t] = v;
        pb ^= 1;
        __syncthreads();
    }
    int run = buf[pb][t] - s;     // exclusive prefix
    for (int i = lo; i < hi; i++) { offsets[i] = run; cursor[i] = run; run += deg[i]; }
    if (t == 1023) offsets[NN] = run;
}

// K3b: CSR scatter — de-indirected payload: src id + alpha pair per slot.
__global__ void k_scatter(const int* __restrict__ ei, const float* __restrict__ alpha,
                          int* __restrict__ cursor,
                          int* __restrict__ src_s, float2* __restrict__ aw) {
    int e = blockIdx.x * blockDim.x + threadIdx.x;
    if (e < NE) {
        int d = ei[NE + e];
        int pos = atomicAdd(cursor + d, 1);
        src_s[pos] = ei[e];
        aw[pos] = *(const float2*)(alpha + (size_t)e*2);
    }
}

// ---------------------------------------------------------------------------
// K4: 1 wave per node: online softmax over contiguous aw, then weighted
// gather-sum of XL rows (2 features per lane).  No LDS, no syncthreads.
// ---------------------------------------------------------------------------
__global__ __launch_bounds__(256) void k_agg(const u16* __restrict__ XL,
                                             const float2* __restrict__ aw,
                                             const int* __restrict__ src_s,
                                             const int* __restrict__ offsets,
                                             u16* __restrict__ out128) {
    const int w = threadIdx.x >> 6, l = threadIdx.x & 63;
    for (int n = blockIdx.x * 4 + w; n < NN; n += gridDim.x * 4) {
        int off = offsets[n], d = offsets[n + 1] - off;
        float acc0 = 0.f, acc1 = 0.f;
        if (d > 0) {
            // online max + sumexp, contiguous reads
            float m0 = -1e30f, m1 = -1e30f, s0 = 0.f, s1 = 0.f;
            for (int j0 = 0; j0 < d; j0 += 64) {
                int j = j0 + l;
                float a0 = -1e30f, a1 = -1e30f;
                if (j < d) { float2 a = aw[off + j]; a0 = a.x; a1 = a.y; }
                float c0 = a0, c1 = a1;
                #pragma unroll
                for (int sh = 32; sh; sh >>= 1) { c0 = fmaxf(c0, __shfl_xor(c0, sh)); c1 = fmaxf(c1, __shfl_xor(c1, sh)); }
                float nm0 = fmaxf(m0, c0), nm1 = fmaxf(m1, c1);
                float e0 = (j < d) ? __expf(a0 - nm0) : 0.f;
                float e1 = (j < d) ? __expf(a1 - nm1) : 0.f;
                #pragma unroll
                for (int sh = 32; sh; sh >>= 1) { e0 += __shfl_xor(e0, sh); e1 += __shfl_xor(e1, sh); }
                s0 = s0 * __expf(m0 - nm0) + e0;
                s1 = s1 * __expf(m1 - nm1) + e1;
                m0 = nm0; m1 = nm1;
            }
            float inv0 = 1.f / (s0 + 1e-16f), inv1 = 1.f / (s1 + 1e-16f);

            // weighted gather-sum; lane l covers features 2l, 2l+1
            for (int j0 = 0; j0 < d; j0 += 64) {
                int j = j0 + l;
                int sj = 0; float w0 = 0.f, w1 = 0.f;
                if (j < d) {
                    sj = src_s[off + j];
                    float2 a = aw[off + j];
                    w0 = __expf(a.x - m0) * inv0;
                    w1 = __expf(a.y - m1) * inv1;
                }
                int cnt = min(64, d - j0);
                #pragma unroll 4
                for (int jj = 0; jj < cnt; jj++) {
                    int s = __shfl(sj, jj);
                    float W0 = __shfl(w0, jj), W1 = __shfl(w1, jj);
                    unsigned v = *(const unsigned*)(XL + (size_t)s*128 + 2*l);
                    union { unsigned u; float f; } f0, f1;
                    f0.u = v << 16; f1.u = v & 0xffff0000u;
                    float Wm = (l < 32) ? W0 : W1;
                    acc0 += Wm * f0.f; acc1 += Wm * f1.f;
                }
            }
        }
        unsigned pk = ((unsigned)(u16)f2bf(acc0)) | (((unsigned)(u16)f2bf(acc1)) << 16);
        *(unsigned*)(out128 + (size_t)n*128 + 2*l) = pk;
    }
}

// ---------------------------------------------------------------------------
// K5: node_out[N,64] = out128[N,128](bf16) @ W_nout + b_nout   (MFMA)
// ---------------------------------------------------------------------------
__global__ __launch_bounds__(256) void k_proj(const u16* __restrict__ out128,
                                              const float* __restrict__ Wn,
                                              const float* __restrict__ bn,
                                              float* __restrict__ node_out) {
    const int w = threadIdx.x >> 6, l = threadIdx.x & 63;
    const int l15 = l & 15, lhi = l >> 4;

    bf16x8 B[4][4];
    #pragma unroll
    for (int t = 0; t < 4; t++) {
        int col = t*16 + l15;
        #pragma unroll
        for (int ks = 0; ks < 4; ks++) {
            #pragma unroll
            for (int j = 0; j < 8; j++) {
                int k = ks*32 + lhi*8 + j;
                B[t][ks][j] = f2bf(Wn[k*64 + col]);
            }
        }
    }

    int nb = blockIdx.x * 64;
    int row = nb + 16*w + l15;
    int rowc = row < NN ? row : NN - 1;
    bf16x8 A[4];
    #pragma unroll
    for (int ks = 0; ks < 4; ks++)
        A[ks] = *(const bf16x8*)(out128 + (size_t)rowc*128 + ks*32 + lhi*8);
    #pragma unroll
    for (int t = 0; t < 4; t++) {
        f32x4 acc = {0.f, 0.f, 0.f, 0.f};
        #pragma unroll
        for (int ks = 0; ks < 4; ks++)
            acc = __builtin_amdgcn_mfma_f32_16x16x32_bf16(A[ks], B[t][ks], acc, 0, 0, 0);
        int col = t*16 + l15;
        float bias = bn[col];
        #pragma unroll
        for (int r = 0; r < 4; r++) {
            int node = nb + 16*w + lhi*4 + r;
            if (node < NN) node_out[(size_t)node*64 + col] = acc[r] + bias;
        }
    }
}

// ---------------------------------------------------------------------------
extern "C" void kernel_launch(void* const* d_in, const int* in_sizes, int n_in,
                              void* d_out, int out_size, void* d_ws, size_t ws_size,
                              hipStream_t stream) {
    const float* x         = (const float*)d_in[0];
    const float* edge_attr = (const float*)d_in[1];
    const int*   ei        = (const int*)  d_in[2];
    const float* Wl        = (const float*)d_in[3];
    const float* bl        = (const float*)d_in[4];
    const float* We        = (const float*)d_in[5];
    const float* be        = (const float*)d_in[6];
    const float* W_att     = (const float*)d_in[7];
    const float* b_att     = (const float*)d_in[8];
    const float* att       = (const float*)d_in[9];
    const float* W_nout    = (const float*)d_in[10];
    const float* b_nout    = (const float*)d_in[11];
    const float* W_eout    = (const float*)d_in[12];
    const float* b_eout    = (const float*)d_in[13];

    float* node_out = (float*)d_out;                 // [N,64]
    float* edge_out = node_out + (size_t)NN * 64;    // [E,32]

    char* p = (char*)d_ws;
    u16* XL      = (u16*)p;            p += (size_t)NN * 128 * 2;   // bf16 [N,128]
    u16* UU      = (u16*)p;            p += (size_t)NN * 256 * 2;   // bf16 [N,256]
    u16* out128  = (u16*)p;            p += (size_t)NN * 128 * 2;   // bf16 [N,128]
    float* alpha = (float*)p;          p += (size_t)NE * 2 * 4;     // [E,2]
    float2* aw   = (float2*)p;         p += (size_t)NE * 2 * 4;     // CSR alpha
    float* WC1   = (float*)p;          p += 128 * 384 * 4;
    float* BC1   = (float*)p;          p += 384 * 4;
    float* WC2   = (float*)p;          p += 64 * 160 * 4;
    float* BC2   = (float*)p;          p += 160 * 4;
    u16*  WC2b   = (u16*)p;            p += 10240 * 2;              // packed B frags
    int*   src_s = (int*)p;            p += (size_t)NE * 4;         // CSR src ids
    int*   deg   = (int*)p;            p += NN * 4;
    int*   offs  = (int*)p;            p += (NN + 1) * 4;
    int*   curs  = (int*)p;            p += NN * 4;

    hipMemsetAsync(deg, 0, NN * sizeof(int), stream);

    k_prep<<<(PREP_TOT + 255) / 256, 256, 0, stream>>>(Wl, bl, We, be, W_att, b_att,
                                                       W_eout, b_eout, WC1, BC1, WC2, BC2);
    k_prep2<<<40, 256, 0, stream>>>(WC2, WC2b);
    k_node<<<625, 256, 0, stream>>>(x, WC1, BC1, XL, UU);
    k_edge<<<2500, 256, 0, stream>>>(edge_attr, ei, UU, WC2b, BC2, att, edge_out, alpha, deg);
    k_scan<<<1, 1024, 0, stream>>>(deg, offs, curs);
    k_scatter<<<(NE + 255) / 256, 256, 0, stream>>>(ei, alpha, curs, src_s, aw);
    k_agg<<<2048, 256, 0, stream>>>(XL, aw, src_s, offs, out128);
    k_proj<<<(NN + 63) / 64, 256, 0, stream>>>(out128, W_nout, b_nout, node_out);
}

// Round 4
// 684.410 us; speedup vs baseline: 2.0759x; 1.0095x over previous
//
#include <hip/hip_runtime.h>
#include <hip/hip_bf16.h>

#define NN 50000
#define NE 1600000

typedef float f32x4 __attribute__((ext_vector_type(4)));
typedef short bf16x8 __attribute__((ext_vector_type(8)));
typedef unsigned short u16;

__device__ inline short f2bf(float f) {
    union { float f; unsigned u; } v; v.f = f;
    unsigned r = v.u + 0x7fffu + ((v.u >> 16) & 1u);   // RNE
    return (short)(r >> 16);
}
__device__ inline float bf2f(u16 u) {
    union { unsigned u; float f; } v; v.u = ((unsigned)u) << 16; return v.f;
}
__device__ inline void pack8(bf16x8& d, float4 p0, float4 p1) {
    d[0]=f2bf(p0.x); d[1]=f2bf(p0.y); d[2]=f2bf(p0.z); d[3]=f2bf(p0.w);
    d[4]=f2bf(p1.x); d[5]=f2bf(p1.y); d[6]=f2bf(p1.z); d[7]=f2bf(p1.w);
}

// ---------------------------------------------------------------------------
// K0: fold weights.
// WC1[128][384]: cols 0-127 Wl, 128-255 U_i (Wl_h @ W_att[0:64]), 256-383 U_j.
// WC2[64][160]: cols 0-31 We@W_eout, 32-159 W_v.
// ---------------------------------------------------------------------------
#define PREP_TOT (128*384 + 384 + 64*160 + 160)

__global__ void k_prep(const float* __restrict__ Wl, const float* __restrict__ bl,
                       const float* __restrict__ We, const float* __restrict__ be,
                       const float* __restrict__ W_att, const float* __restrict__ b_att,
                       const float* __restrict__ W_eout, const float* __restrict__ b_eout,
                       float* __restrict__ WC1, float* __restrict__ BC1,
                       float* __restrict__ WC2, float* __restrict__ BC2) {
    int id = blockIdx.x * blockDim.x + threadIdx.x;
    if (id < 128*384) {
        int k = id / 384, col = id % 384;
        float v;
        if (col < 128) v = Wl[k*128 + col];
        else {
            int role = (col - 128) >> 7;          // 0 = u_i(dst), 1 = u_j(src)
            int hc = (col - 128) & 127, h = hc >> 6, a = hc & 63;
            float s = 0.f;
            for (int c = 0; c < 64; c++) s += Wl[k*128 + h*64 + c] * W_att[(role*64 + c)*64 + a];
            v = s;
        }
        WC1[id] = v;
    } else if (id < 128*384 + 384) {
        int col = id - 128*384;
        float v;
        if (col < 128) v = bl[col];
        else {
            int role = (col - 128) >> 7;
            int hc = (col - 128) & 127, h = hc >> 6, a = hc & 63;
            float s = 0.f;
            for (int c = 0; c < 64; c++) s += bl[h*64 + c] * W_att[(role*64 + c)*64 + a];
            v = s;
        }
        BC1[col] = v;
    } else if (id < 128*384 + 384 + 64*160) {
        int id2 = id - (128*384 + 384);
        int k = id2 / 160, col = id2 % 160;
        float s = 0.f;
        if (col < 32) { for (int m = 0; m < 64; m++) s += We[k*64 + m] * W_eout[m*32 + col]; }
        else {
            int hc = col - 32, h = hc >> 6, a = hc & 63;
            for (int j = 0; j < 32; j++) s += We[k*64 + h*32 + j] * W_att[(128 + j)*64 + a];
        }
        WC2[id2] = s;
    } else if (id < PREP_TOT) {
        int col = id - (128*384 + 384 + 64*160);
        float s = 0.f;
        if (col < 32) { for (int m = 0; m < 64; m++) s += be[m] * W_eout[m*32 + col]; s += b_eout[col]; }
        else {
            int hc = col - 32, h = hc >> 6, a = hc & 63;
            for (int j = 0; j < 32; j++) s += be[h*32 + j] * W_att[(128 + j)*64 + a];
            s += b_att[a];
        }
        BC2[col] = s;
    }
}

// K0b: pre-pack WC2 into per-lane bf16 MFMA B-fragments.
__global__ void k_prep2(const float* __restrict__ WC2, u16* __restrict__ WC2b) {
    int id = blockIdx.x * blockDim.x + threadIdx.x;
    if (id < 10240) {
        int j = id & 7, l = (id >> 3) & 63, ks = (id >> 9) & 1, t = id >> 10;
        int col = t*16 + (l & 15);
        int k = ks*32 + (l >> 4)*8 + j;
        WC2b[id] = (u16)f2bf(WC2[k*160 + col]);
    }
}

// K0c: dst-degree histogram (runs before k_edge so CSR offsets exist).
__global__ void k_deg(const int* __restrict__ ei, int* __restrict__ deg) {
    int e = blockIdx.x * blockDim.x + threadIdx.x;
    if (e < NE) atomicAdd(deg + ei[NE + e], 1);
}

// ---------------------------------------------------------------------------
// K1: node transform -> XL[N,128] bf16 (xl) and UU[N,256] bf16 (u_i|u_j).
// ---------------------------------------------------------------------------
__global__ __launch_bounds__(256) void k_node(const float* __restrict__ x,
                                              const float* __restrict__ WC1,
                                              const float* __restrict__ BC1,
                                              u16* __restrict__ XL,
                                              u16* __restrict__ UU) {
    const int w = threadIdx.x >> 6, l = threadIdx.x & 63;
    const int l15 = l & 15, lhi = l >> 4;

    bf16x8 B[6][4];
    #pragma unroll
    for (int t = 0; t < 6; t++) {
        int col = (6*w + t)*16 + l15;
        #pragma unroll
        for (int ks = 0; ks < 4; ks++) {
            #pragma unroll
            for (int j = 0; j < 8; j++) {
                int k = ks*32 + lhi*8 + j;
                B[t][ks][j] = f2bf(WC1[k*384 + col]);
            }
        }
    }

    for (int nb = blockIdx.x * 16; nb < NN; nb += gridDim.x * 16) {
        int row = nb + l15;
        bf16x8 A[4];
        #pragma unroll
        for (int ks = 0; ks < 4; ks++) {
            const float* p = x + (size_t)row*128 + ks*32 + lhi*8;
            pack8(A[ks], *(const float4*)p, *(const float4*)(p + 4));
        }
        #pragma unroll
        for (int t = 0; t < 6; t++) {
            f32x4 acc = {0.f, 0.f, 0.f, 0.f};
            #pragma unroll
            for (int ks = 0; ks < 4; ks++)
                acc = __builtin_amdgcn_mfma_f32_16x16x32_bf16(A[ks], B[t][ks], acc, 0, 0, 0);
            int col = (6*w + t)*16 + l15;
            float bias = BC1[col];
            #pragma unroll
            for (int r = 0; r < 4; r++) {
                int node = nb + lhi*4 + r;
                float v = acc[r] + bias;
                if (col < 128) XL[(size_t)node*128 + col] = (u16)f2bf(v);
                else           UU[(size_t)node*256 + (col - 128)] = (u16)f2bf(v);
            }
        }
    }
}

// ---------------------------------------------------------------------------
// K2: wave-autonomous edge kernel, 16 edges/wave/iter, no __syncthreads.
//   Phase 1: C[16][160] = attr @ WC2 (MFMA); t<2 -> edge_out, t>=2 -> bf16 LDS.
//   Phase 2: lanes = (edge, head, half); 32-val reduction; shfl combine;
//            lane0-of-4 writes CSR slot directly (atomic cursor).
// LDS: per-edge stride 138 u16 (word stride 69 -> e_loc*5 mod 32 distinct).
// ---------------------------------------------------------------------------
__global__ __launch_bounds__(256) void k_edge(const float* __restrict__ attr,
                                              const int* __restrict__ ei,
                                              const u16* __restrict__ UU,
                                              const u16* __restrict__ WC2b,
                                              const float* __restrict__ BC2,
                                              const float* __restrict__ att,
                                              float* __restrict__ edge_out,
                                              int* __restrict__ curs,
                                              int* __restrict__ src_s,
                                              float2* __restrict__ aw) {
    __shared__ u16 vlds[4][16 * 138];
    __shared__ float att_p[131];
    const int tid = threadIdx.x;
    const int w = tid >> 6, l = tid & 63, l15 = l & 15, lhi = l >> 4;

    if (tid < 128) {
        int h = tid >> 6, rem = tid & 63, half = rem >> 5, q = rem & 31;
        att_p[h*66 + half*33 + q] = att[tid];
    }

    bf16x8 B[10][2];
    #pragma unroll
    for (int t = 0; t < 10; t++)
        #pragma unroll
        for (int ks = 0; ks < 2; ks++)
            B[t][ks] = *(const bf16x8*)(WC2b + (size_t)((t*2 + ks)*64 + l)*8);

    u16* vw = vlds[w];
    // phase-2 lane roles
    const int e_loc = l >> 2, h2 = (l >> 1) & 1, half2 = l & 1;
    const u16*  vbase = vw + e_loc*138 + h2*64 + half2*32;
    const float* abase = att_p + h2*66 + half2*33;

    __syncthreads();   // att_p ready (once)

    for (int e0 = (blockIdx.x*4 + w)*16; e0 < NE; e0 += gridDim.x*64) {
        // edge ids early (latency hides under attr loads + cvt + MFMA)
        int e = e0 + e_loc;
        int src = ei[e], dst = ei[NE + e];

        int row = e0 + l15;
        bf16x8 A[2];
        #pragma unroll
        for (int ks = 0; ks < 2; ks++) {
            const float* p = attr + (size_t)row*64 + ks*32 + lhi*8;
            pack8(A[ks], *(const float4*)p, *(const float4*)(p + 4));
        }
        #pragma unroll
        for (int t = 0; t < 10; t++) {
            f32x4 acc = {0.f, 0.f, 0.f, 0.f};
            acc = __builtin_amdgcn_mfma_f32_16x16x32_bf16(A[0], B[t][0], acc, 0, 0, 0);
            acc = __builtin_amdgcn_mfma_f32_16x16x32_bf16(A[1], B[t][1], acc, 0, 0, 0);
            int col = t*16 + l15;
            float bias = BC2[col];
            if (t < 2) {
                #pragma unroll
                for (int r = 0; r < 4; r++) {
                    int er = e0 + lhi*4 + r;
                    edge_out[(size_t)er*32 + col] = acc[r] + bias;
                }
            } else {
                int hc = col - 32;                 // 0..127, contiguous per edge
                #pragma unroll
                for (int r = 0; r < 4; r++)
                    vw[(lhi*4 + r)*138 + hc] = (u16)f2bf(acc[r] + bias);
            }
        }

        // ---- phase 2 (same wave; lgkmcnt ordering only) ----
        const u16* up = UU + (size_t)dst*256 + h2*64 + half2*32;
        const u16* vp = UU + (size_t)src*256 + 128 + h2*64 + half2*32;
        float asum = 0.f;
        #pragma unroll
        for (int q4 = 0; q4 < 4; q4++) {
            bf16x8 au = *(const bf16x8*)(up + q4*8);
            bf16x8 bu = *(const bf16x8*)(vp + q4*8);
            #pragma unroll
            for (int j = 0; j < 8; j++) {
                int q = q4*8 + j;
                float s = bf2f(vbase[q]) + bf2f((u16)au[j]) + bf2f((u16)bu[j]);
                s = s > 0.f ? s : 0.2f * s;
                asum += s * abase[q];
            }
        }
        asum += __shfl_xor(asum, 1);          // lanes 0,1: alpha_h0 | lanes 2,3: alpha_h1
        float aother = __shfl_xor(asum, 2);   // lane 0 gets alpha_h1
        if ((l & 3) == 0) {
            int pos = atomicAdd(curs + dst, 1);
            src_s[pos] = src;
            aw[pos] = make_float2(asum, aother);
        }
    }
}

// ---------------------------------------------------------------------------
// K3: exclusive scan of deg -> offsets, cursor.  Single block, 1024 threads.
// ---------------------------------------------------------------------------
__global__ __launch_bounds__(1024) void k_scan(const int* __restrict__ deg,
                                               int* __restrict__ offsets,
                                               int* __restrict__ cursor) {
    __shared__ int buf[2][1024];
    int t = threadIdx.x;
    const int chunk = (NN + 1023) / 1024;
    int lo = t * chunk, hi = lo + chunk; if (hi > NN) hi = NN; if (lo > NN) lo = NN;
    int s = 0;
    for (int i = lo; i < hi; i++) s += deg[i];
    int pb = 0;
    buf[0][t] = s;
    __syncthreads();
    for (int d = 1; d < 1024; d <<= 1) {
        int v = buf[pb][t] + ((t >= d) ? buf[pb][t - d] : 0);
        buf[pb ^ 1][t] = v;
        pb ^= 1;
        __syncthreads();
    }
    int run = buf[pb][t] - s;     // exclusive prefix
    for (int i = lo; i < hi; i++) { offsets[i] = run; cursor[i] = run; run += deg[i]; }
    if (t == 1023) offsets[NN] = run;
}

// ---------------------------------------------------------------------------
// K4: 1 wave per node: online softmax over contiguous aw, then weighted
// gather-sum of XL rows (2 features per lane).  No LDS, no syncthreads.
// ---------------------------------------------------------------------------
__global__ __launch_bounds__(256) void k_agg(const u16* __restrict__ XL,
                                             const float2* __restrict__ aw,
                                             const int* __restrict__ src_s,
                                             const int* __restrict__ offsets,
                                             u16* __restrict__ out128) {
    const int w = threadIdx.x >> 6, l = threadIdx.x & 63;
    for (int n = blockIdx.x * 4 + w; n < NN; n += gridDim.x * 4) {
        int off = offsets[n], d = offsets[n + 1] - off;
        float acc0 = 0.f, acc1 = 0.f;
        if (d > 0) {
            // online max + sumexp, contiguous reads
            float m0 = -1e30f, m1 = -1e30f, s0 = 0.f, s1 = 0.f;
            for (int j0 = 0; j0 < d; j0 += 64) {
                int j = j0 + l;
                float a0 = -1e30f, a1 = -1e30f;
                if (j < d) { float2 a = aw[off + j]; a0 = a.x; a1 = a.y; }
                float c0 = a0, c1 = a1;
                #pragma unroll
                for (int sh = 32; sh; sh >>= 1) { c0 = fmaxf(c0, __shfl_xor(c0, sh)); c1 = fmaxf(c1, __shfl_xor(c1, sh)); }
                float nm0 = fmaxf(m0, c0), nm1 = fmaxf(m1, c1);
                float e0 = (j < d) ? __expf(a0 - nm0) : 0.f;
                float e1 = (j < d) ? __expf(a1 - nm1) : 0.f;
                #pragma unroll
                for (int sh = 32; sh; sh >>= 1) { e0 += __shfl_xor(e0, sh); e1 += __shfl_xor(e1, sh); }
                s0 = s0 * __expf(m0 - nm0) + e0;
                s1 = s1 * __expf(m1 - nm1) + e1;
                m0 = nm0; m1 = nm1;
            }
            float inv0 = 1.f / (s0 + 1e-16f), inv1 = 1.f / (s1 + 1e-16f);

            // weighted gather-sum; lane l covers features 2l, 2l+1
            for (int j0 = 0; j0 < d; j0 += 64) {
                int j = j0 + l;
                int sj = 0; float w0 = 0.f, w1 = 0.f;
                if (j < d) {
                    sj = src_s[off + j];
                    float2 a = aw[off + j];
                    w0 = __expf(a.x - m0) * inv0;
                    w1 = __expf(a.y - m1) * inv1;
                }
                int cnt = min(64, d - j0);
                #pragma unroll 8
                for (int jj = 0; jj < cnt; jj++) {
                    int s = __shfl(sj, jj);
                    float W0 = __shfl(w0, jj), W1 = __shfl(w1, jj);
                    unsigned v = *(const unsigned*)(XL + (size_t)s*128 + 2*l);
                    union { unsigned u; float f; } f0, f1;
                    f0.u = v << 16; f1.u = v & 0xffff0000u;
                    float Wm = (l < 32) ? W0 : W1;
                    acc0 += Wm * f0.f; acc1 += Wm * f1.f;
                }
            }
        }
        unsigned pk = ((unsigned)(u16)f2bf(acc0)) | (((unsigned)(u16)f2bf(acc1)) << 16);
        *(unsigned*)(out128 + (size_t)n*128 + 2*l) = pk;
    }
}

// ---------------------------------------------------------------------------
// K5: node_out[N,64] = out128[N,128](bf16) @ W_nout + b_nout   (MFMA)
// ---------------------------------------------------------------------------
__global__ __launch_bounds__(256) void k_proj(const u16* __restrict__ out128,
                                              const float* __restrict__ Wn,
                                              const float* __restrict__ bn,
                                              float* __restrict__ node_out) {
    const int w = threadIdx.x >> 6, l = threadIdx.x & 63;
    const int l15 = l & 15, lhi = l >> 4;

    bf16x8 B[4][4];
    #pragma unroll
    for (int t = 0; t < 4; t++) {
        int col = t*16 + l15;
        #pragma unroll
        for (int ks = 0; ks < 4; ks++) {
            #pragma unroll
            for (int j = 0; j < 8; j++) {
                int k = ks*32 + lhi*8 + j;
                B[t][ks][j] = f2bf(Wn[k*64 + col]);
            }
        }
    }

    int nb = blockIdx.x * 64;
    int row = nb + 16*w + l15;
    int rowc = row < NN ? row : NN - 1;
    bf16x8 A[4];
    #pragma unroll
    for (int ks = 0; ks < 4; ks++)
        A[ks] = *(const bf16x8*)(out128 + (size_t)rowc*128 + ks*32 + lhi*8);
    #pragma unroll
    for (int t = 0; t < 4; t++) {
        f32x4 acc = {0.f, 0.f, 0.f, 0.f};
        #pragma unroll
        for (int ks = 0; ks < 4; ks++)
            acc = __builtin_amdgcn_mfma_f32_16x16x32_bf16(A[ks], B[t][ks], acc, 0, 0, 0);
        int col = t*16 + l15;
        float bias = bn[col];
        #pragma unroll
        for (int r = 0; r < 4; r++) {
            int node = nb + 16*w + lhi*4 + r;
            if (node < NN) node_out[(size_t)node*64 + col] = acc[r] + bias;
        }
    }
}

// ---------------------------------------------------------------------------
extern "C" void kernel_launch(void* const* d_in, const int* in_sizes, int n_in,
                              void* d_out, int out_size, void* d_ws, size_t ws_size,
                              hipStream_t stream) {
    const float* x         = (const float*)d_in[0];
    const float* edge_attr = (const float*)d_in[1];
    const int*   ei        = (const int*)  d_in[2];
    const float* Wl        = (const float*)d_in[3];
    const float* bl        = (const float*)d_in[4];
    const float* We        = (const float*)d_in[5];
    const float* be        = (const float*)d_in[6];
    const float* W_att     = (const float*)d_in[7];
    const float* b_att     = (const float*)d_in[8];
    const float* att       = (const float*)d_in[9];
    const float* W_nout    = (const float*)d_in[10];
    const float* b_nout    = (const float*)d_in[11];
    const float* W_eout    = (const float*)d_in[12];
    const float* b_eout    = (const float*)d_in[13];

    float* node_out = (float*)d_out;                 // [N,64]
    float* edge_out = node_out + (size_t)NN * 64;    // [E,32]

    char* p = (char*)d_ws;
    u16* XL      = (u16*)p;            p += (size_t)NN * 128 * 2;   // bf16 [N,128]
    u16* UU      = (u16*)p;            p += (size_t)NN * 256 * 2;   // bf16 [N,256]
    u16* out128  = (u16*)p;            p += (size_t)NN * 128 * 2;   // bf16 [N,128]
    float2* aw   = (float2*)p;         p += (size_t)NE * 2 * 4;     // CSR alpha pairs
    float* WC1   = (float*)p;          p += 128 * 384 * 4;
    float* BC1   = (float*)p;          p += 384 * 4;
    float* WC2   = (float*)p;          p += 64 * 160 * 4;
    float* BC2   = (float*)p;          p += 160 * 4;
    u16*  WC2b   = (u16*)p;            p += 10240 * 2;              // packed B frags
    int*   src_s = (int*)p;            p += (size_t)NE * 4;         // CSR src ids
    int*   deg   = (int*)p;            p += NN * 4;
    int*   offs  = (int*)p;            p += (NN + 1) * 4;
    int*   curs  = (int*)p;            p += NN * 4;

    hipMemsetAsync(deg, 0, NN * sizeof(int), stream);

    k_prep<<<(PREP_TOT + 255) / 256, 256, 0, stream>>>(Wl, bl, We, be, W_att, b_att,
                                                       W_eout, b_eout, WC1, BC1, WC2, BC2);
    k_prep2<<<40, 256, 0, stream>>>(WC2, WC2b);
    k_deg<<<(NE + 255) / 256, 256, 0, stream>>>(ei, deg);
    k_scan<<<1, 1024, 0, stream>>>(deg, offs, curs);
    k_node<<<625, 256, 0, stream>>>(x, WC1, BC1, XL, UU);
    k_edge<<<2048, 256, 0, stream>>>(edge_attr, ei, UU, WC2b, BC2, att,
                                     edge_out, curs, src_s, aw);
    k_agg<<<2048, 256, 0, stream>>>(XL, aw, src_s, offs, out128);
    k_proj<<<(NN + 63) / 64, 256, 0, stream>>>(out128, W_nout, b_nout, node_out);
}

// Round 5
// 584.356 us; speedup vs baseline: 2.4314x; 1.1712x over previous
//
#include <hip/hip_runtime.h>
#include <hip/hip_bf16.h>

#define NN 50000
#define NE 1600000

typedef float f32x4 __attribute__((ext_vector_type(4)));
typedef short bf16x8 __attribute__((ext_vector_type(8)));
typedef unsigned short u16;

__device__ inline short f2bf(float f) {
    union { float f; unsigned u; } v; v.f = f;
    unsigned r = v.u + 0x7fffu + ((v.u >> 16) & 1u);   // RNE
    return (short)(r >> 16);
}
__device__ inline float bf2f(u16 u) {
    union { unsigned u; float f; } v; v.u = ((unsigned)u) << 16; return v.f;
}
__device__ inline void pack8(bf16x8& d, float4 p0, float4 p1) {
    d[0]=f2bf(p0.x); d[1]=f2bf(p0.y); d[2]=f2bf(p0.z); d[3]=f2bf(p0.w);
    d[4]=f2bf(p1.x); d[5]=f2bf(p1.y); d[6]=f2bf(p1.z); d[7]=f2bf(p1.w);
}

// ---------------------------------------------------------------------------
// K0: fold weights.
// WC1[128][384]: cols 0-127 Wl, 128-255 U_i (Wl_h @ W_att[0:64]), 256-383 U_j.
// WC2[64][160]: cols 0-31 We@W_eout, 32-159 W_v.
// ---------------------------------------------------------------------------
#define PREP_TOT (128*384 + 384 + 64*160 + 160)

__global__ void k_prep(const float* __restrict__ Wl, const float* __restrict__ bl,
                       const float* __restrict__ We, const float* __restrict__ be,
                       const float* __restrict__ W_att, const float* __restrict__ b_att,
                       const float* __restrict__ W_eout, const float* __restrict__ b_eout,
                       float* __restrict__ WC1, float* __restrict__ BC1,
                       float* __restrict__ WC2, float* __restrict__ BC2) {
    int id = blockIdx.x * blockDim.x + threadIdx.x;
    if (id < 128*384) {
        int k = id / 384, col = id % 384;
        float v;
        if (col < 128) v = Wl[k*128 + col];
        else {
            int role = (col - 128) >> 7;          // 0 = u_i(dst), 1 = u_j(src)
            int hc = (col - 128) & 127, h = hc >> 6, a = hc & 63;
            float s = 0.f;
            for (int c = 0; c < 64; c++) s += Wl[k*128 + h*64 + c] * W_att[(role*64 + c)*64 + a];
            v = s;
        }
        WC1[id] = v;
    } else if (id < 128*384 + 384) {
        int col = id - 128*384;
        float v;
        if (col < 128) v = bl[col];
        else {
            int role = (col - 128) >> 7;
            int hc = (col - 128) & 127, h = hc >> 6, a = hc & 63;
            float s = 0.f;
            for (int c = 0; c < 64; c++) s += bl[h*64 + c] * W_att[(role*64 + c)*64 + a];
            v = s;
        }
        BC1[col] = v;
    } else if (id < 128*384 + 384 + 64*160) {
        int id2 = id - (128*384 + 384);
        int k = id2 / 160, col = id2 % 160;
        float s = 0.f;
        if (col < 32) { for (int m = 0; m < 64; m++) s += We[k*64 + m] * W_eout[m*32 + col]; }
        else {
            int hc = col - 32, h = hc >> 6, a = hc & 63;
            for (int j = 0; j < 32; j++) s += We[k*64 + h*32 + j] * W_att[(128 + j)*64 + a];
        }
        WC2[id2] = s;
    } else if (id < PREP_TOT) {
        int col = id - (128*384 + 384 + 64*160);
        float s = 0.f;
        if (col < 32) { for (int m = 0; m < 64; m++) s += be[m] * W_eout[m*32 + col]; s += b_eout[col]; }
        else {
            int hc = col - 32, h = hc >> 6, a = hc & 63;
            for (int j = 0; j < 32; j++) s += be[h*32 + j] * W_att[(128 + j)*64 + a];
            s += b_att[a];
        }
        BC2[col] = s;
    }
}

// K0b: pre-pack WC2 into per-lane bf16 MFMA B-fragments.
__global__ void k_prep2(const float* __restrict__ WC2, u16* __restrict__ WC2b) {
    int id = blockIdx.x * blockDim.x + threadIdx.x;
    if (id < 10240) {
        int j = id & 7, l = (id >> 3) & 63, ks = (id >> 9) & 1, t = id >> 10;
        int col = t*16 + (l & 15);
        int k = ks*32 + (l >> 4)*8 + j;
        WC2b[id] = (u16)f2bf(WC2[k*160 + col]);
    }
}

// K0c: dst-degree histogram (runs before k_edge so CSR offsets exist).
__global__ void k_deg(const int* __restrict__ ei, int* __restrict__ deg) {
    int e = blockIdx.x * blockDim.x + threadIdx.x;
    if (e < NE) atomicAdd(deg + ei[NE + e], 1);
}

// ---------------------------------------------------------------------------
// K1: node transform -> XL[N,128] bf16 (xl) and UU[N,256] bf16 (u_i|u_j).
// ---------------------------------------------------------------------------
__global__ __launch_bounds__(256) void k_node(const float* __restrict__ x,
                                              const float* __restrict__ WC1,
                                              const float* __restrict__ BC1,
                                              u16* __restrict__ XL,
                                              u16* __restrict__ UU) {
    const int w = threadIdx.x >> 6, l = threadIdx.x & 63;
    const int l15 = l & 15, lhi = l >> 4;

    bf16x8 B[6][4];
    #pragma unroll
    for (int t = 0; t < 6; t++) {
        int col = (6*w + t)*16 + l15;
        #pragma unroll
        for (int ks = 0; ks < 4; ks++) {
            #pragma unroll
            for (int j = 0; j < 8; j++) {
                int k = ks*32 + lhi*8 + j;
                B[t][ks][j] = f2bf(WC1[k*384 + col]);
            }
        }
    }

    for (int nb = blockIdx.x * 16; nb < NN; nb += gridDim.x * 16) {
        int row = nb + l15;
        bf16x8 A[4];
        #pragma unroll
        for (int ks = 0; ks < 4; ks++) {
            const float* p = x + (size_t)row*128 + ks*32 + lhi*8;
            pack8(A[ks], *(const float4*)p, *(const float4*)(p + 4));
        }
        #pragma unroll
        for (int t = 0; t < 6; t++) {
            f32x4 acc = {0.f, 0.f, 0.f, 0.f};
            #pragma unroll
            for (int ks = 0; ks < 4; ks++)
                acc = __builtin_amdgcn_mfma_f32_16x16x32_bf16(A[ks], B[t][ks], acc, 0, 0, 0);
            int col = (6*w + t)*16 + l15;
            float bias = BC1[col];
            #pragma unroll
            for (int r = 0; r < 4; r++) {
                int node = nb + lhi*4 + r;
                float v = acc[r] + bias;
                if (col < 128) XL[(size_t)node*128 + col] = (u16)f2bf(v);
                else           UU[(size_t)node*256 + (col - 128)] = (u16)f2bf(v);
            }
        }
    }
}

// ---------------------------------------------------------------------------
// K2: wave-autonomous, software-pipelined edge kernel. 16 edges/wave/iter.
// Issue order per iter: atomic (CSR pos) -> attr loads -> COALESCED UU gathers
// (16 contiguous lanes per 256B u-row) -> next-iter ei prefetch -> cvt+MFMA
// (t<2 -> edge_out, t>=2 -> bf16 LDS) -> per-q reduce (shfl 1,2,4; 8 pairs
// heads) -> one 16B CSR store {a0,a1,src}.  No __syncthreads anywhere.
// ---------------------------------------------------------------------------
__global__ __launch_bounds__(256) void k_edge(const float* __restrict__ attr,
                                              const int* __restrict__ ei,
                                              const u16* __restrict__ UU,
                                              const u16* __restrict__ WC2b,
                                              const float* __restrict__ BC2,
                                              const float* __restrict__ att,
                                              float* __restrict__ edge_out,
                                              int* __restrict__ curs,
                                              float4* __restrict__ aw) {
    __shared__ u16 vlds[4][16 * 136];
    const int tid = threadIdx.x;
    const int w = tid >> 6, l = tid & 63, l15 = l & 15, lhi = l >> 4;

    bf16x8 B[10][2];
    #pragma unroll
    for (int t = 0; t < 10; t++)
        #pragma unroll
        for (int ks = 0; ks < 2; ks++)
            B[t][ks] = *(const bf16x8*)(WC2b + (size_t)((t*2 + ks)*64 + l)*8);

    // per-lane attention weights for chunk c=l15 (head = c>>3)
    float att_c[8];
    {
        int base = (l15 >> 3)*64 + (l15 & 7)*8;
        float4 t0 = *(const float4*)(att + base);
        float4 t1 = *(const float4*)(att + base + 4);
        att_c[0]=t0.x; att_c[1]=t0.y; att_c[2]=t0.z; att_c[3]=t0.w;
        att_c[4]=t1.x; att_c[5]=t1.y; att_c[6]=t1.z; att_c[7]=t1.w;
    }

    u16* vw = vlds[w];
    const int STRIDE = gridDim.x * 64;
    int e0 = (blockIdx.x*4 + w)*16;
    int srcP = 0, dstP = 0;
    if (l < 16) { srcP = ei[e0 + l]; dstP = ei[NE + e0 + l]; }

    for (; e0 < NE; e0 += STRIDE) {
        // --- CSR slot (result needed only at iter end) ---
        int posP = 0;
        if (l < 16) posP = atomicAdd(curs + dstP, 1);

        // --- attr loads issued first (oldest in vmcnt queue) ---
        const float* pa = attr + (size_t)(e0 + l15)*64 + lhi*8;
        float4 ar00 = *(const float4*)(pa);
        float4 ar01 = *(const float4*)(pa + 4);
        float4 ar10 = *(const float4*)(pa + 32);
        float4 ar11 = *(const float4*)(pa + 36);

        // --- coalesced UU gathers: lane = (edge 4q+lhi, chunk l15) ---
        bf16x8 ug[4], vg[4];
        int pq[4], sq[4];
        #pragma unroll
        for (int q = 0; q < 4; q++) {
            int eq = 4*q + lhi;
            int de = __shfl(dstP, eq), se = __shfl(srcP, eq);
            pq[q] = __shfl(posP, eq);
            sq[q] = se;
            ug[q] = *(const bf16x8*)(UU + (size_t)de*256 + l15*8);
            vg[q] = *(const bf16x8*)(UU + (size_t)se*256 + 128 + l15*8);
        }

        // --- prefetch next iter's edge ids ---
        {
            int e0n = e0 + STRIDE;
            int eb = (e0n < NE) ? e0n : 0;
            if (l < 16) { srcP = ei[eb + l]; dstP = ei[NE + eb + l]; }
        }

        // --- cvt + MFMA (waits attr only; gathers stay in flight) ---
        bf16x8 A[2];
        pack8(A[0], ar00, ar01);
        pack8(A[1], ar10, ar11);
        #pragma unroll
        for (int t = 0; t < 10; t++) {
            f32x4 acc = {0.f, 0.f, 0.f, 0.f};
            acc = __builtin_amdgcn_mfma_f32_16x16x32_bf16(A[0], B[t][0], acc, 0, 0, 0);
            acc = __builtin_amdgcn_mfma_f32_16x16x32_bf16(A[1], B[t][1], acc, 0, 0, 0);
            int col = t*16 + l15;
            float bias = BC2[col];
            if (t < 2) {
                #pragma unroll
                for (int r = 0; r < 4; r++) {
                    int er = e0 + lhi*4 + r;
                    edge_out[(size_t)er*32 + col] = acc[r] + bias;
                }
            } else {
                int hc = col - 32;                 // 0..127
                #pragma unroll
                for (int r = 0; r < 4; r++)
                    vw[(lhi*4 + r)*136 + hc] = (u16)f2bf(acc[r] + bias);
            }
        }

        // --- phase 2: per q, edge eq = 4q+lhi, this lane covers 8 a-values ---
        #pragma unroll
        for (int q = 0; q < 4; q++) {
            int eq = 4*q + lhi;
            bf16x8 vv = *(const bf16x8*)(vw + eq*136 + l15*8);
            float part = 0.f;
            #pragma unroll
            for (int j = 0; j < 8; j++) {
                float s = bf2f((u16)vv[j]) + bf2f((u16)ug[q][j]) + bf2f((u16)vg[q][j]);
                s = fmaxf(s, 0.2f * s);            // leaky relu
                part = fmaf(s, att_c[j], part);
            }
            part += __shfl_xor(part, 1);
            part += __shfl_xor(part, 2);
            part += __shfl_xor(part, 4);           // lane c=0: head0, c=8: head1
            float a1 = __shfl_xor(part, 8);        // c=0 receives head1
            if (l15 == 0) {
                float4 pay;
                pay.x = part; pay.y = a1;
                pay.z = __int_as_float(sq[q]); pay.w = 0.f;
                aw[pq[q]] = pay;
            }
        }
    }
}

// ---------------------------------------------------------------------------
// K3: exclusive scan of deg -> offsets, cursor.  Single block, 1024 threads.
// ---------------------------------------------------------------------------
__global__ __launch_bounds__(1024) void k_scan(const int* __restrict__ deg,
                                               int* __restrict__ offsets,
                                               int* __restrict__ cursor) {
    __shared__ int buf[2][1024];
    int t = threadIdx.x;
    const int chunk = (NN + 1023) / 1024;
    int lo = t * chunk, hi = lo + chunk; if (hi > NN) hi = NN; if (lo > NN) lo = NN;
    int s = 0;
    for (int i = lo; i < hi; i++) s += deg[i];
    int pb = 0;
    buf[0][t] = s;
    __syncthreads();
    for (int d = 1; d < 1024; d <<= 1) {
        int v = buf[pb][t] + ((t >= d) ? buf[pb][t - d] : 0);
        buf[pb ^ 1][t] = v;
        pb ^= 1;
        __syncthreads();
    }
    int run = buf[pb][t] - s;     // exclusive prefix
    for (int i = lo; i < hi; i++) { offsets[i] = run; cursor[i] = run; run += deg[i]; }
    if (t == 1023) offsets[NN] = run;
}

// ---------------------------------------------------------------------------
// K4: 1 wave per node: online softmax over contiguous aw {a0,a1,src}, then
// weighted gather-sum of XL rows (2 features per lane).  No LDS, no syncs.
// ---------------------------------------------------------------------------
__global__ __launch_bounds__(256) void k_agg(const u16* __restrict__ XL,
                                             const float4* __restrict__ aw,
                                             const int* __restrict__ offsets,
                                             u16* __restrict__ out128) {
    const int w = threadIdx.x >> 6, l = threadIdx.x & 63;
    for (int n = blockIdx.x * 4 + w; n < NN; n += gridDim.x * 4) {
        int off = offsets[n], d = offsets[n + 1] - off;
        float acc0 = 0.f, acc1 = 0.f;
        if (d > 0) {
            // online max + sumexp, contiguous reads
            float m0 = -1e30f, m1 = -1e30f, s0 = 0.f, s1 = 0.f;
            for (int j0 = 0; j0 < d; j0 += 64) {
                int j = j0 + l;
                float a0 = -1e30f, a1 = -1e30f;
                if (j < d) { float4 a = aw[off + j]; a0 = a.x; a1 = a.y; }
                float c0 = a0, c1 = a1;
                #pragma unroll
                for (int sh = 32; sh; sh >>= 1) { c0 = fmaxf(c0, __shfl_xor(c0, sh)); c1 = fmaxf(c1, __shfl_xor(c1, sh)); }
                float nm0 = fmaxf(m0, c0), nm1 = fmaxf(m1, c1);
                float e0 = (j < d) ? __expf(a0 - nm0) : 0.f;
                float e1 = (j < d) ? __expf(a1 - nm1) : 0.f;
                #pragma unroll
                for (int sh = 32; sh; sh >>= 1) { e0 += __shfl_xor(e0, sh); e1 += __shfl_xor(e1, sh); }
                s0 = s0 * __expf(m0 - nm0) + e0;
                s1 = s1 * __expf(m1 - nm1) + e1;
                m0 = nm0; m1 = nm1;
            }
            float inv0 = 1.f / (s0 + 1e-16f), inv1 = 1.f / (s1 + 1e-16f);

            // weighted gather-sum; lane l covers features 2l, 2l+1
            for (int j0 = 0; j0 < d; j0 += 64) {
                int j = j0 + l;
                int sj = 0; float w0 = 0.f, w1 = 0.f;
                if (j < d) {
                    float4 a = aw[off + j];
                    sj = __float_as_int(a.z);
                    w0 = __expf(a.x - m0) * inv0;
                    w1 = __expf(a.y - m1) * inv1;
                }
                int cnt = min(64, d - j0);
                #pragma unroll 8
                for (int jj = 0; jj < cnt; jj++) {
                    int s = __shfl(sj, jj);
                    float W0 = __shfl(w0, jj), W1 = __shfl(w1, jj);
                    unsigned v = *(const unsigned*)(XL + (size_t)s*128 + 2*l);
                    union { unsigned u; float f; } f0, f1;
                    f0.u = v << 16; f1.u = v & 0xffff0000u;
                    float Wm = (l < 32) ? W0 : W1;
                    acc0 += Wm * f0.f; acc1 += Wm * f1.f;
                }
            }
        }
        unsigned pk = ((unsigned)(u16)f2bf(acc0)) | (((unsigned)(u16)f2bf(acc1)) << 16);
        *(unsigned*)(out128 + (size_t)n*128 + 2*l) = pk;
    }
}

// ---------------------------------------------------------------------------
// K5: node_out[N,64] = out128[N,128](bf16) @ W_nout + b_nout   (MFMA)
// ---------------------------------------------------------------------------
__global__ __launch_bounds__(256) void k_proj(const u16* __restrict__ out128,
                                              const float* __restrict__ Wn,
                                              const float* __restrict__ bn,
                                              float* __restrict__ node_out) {
    const int w = threadIdx.x >> 6, l = threadIdx.x & 63;
    const int l15 = l & 15, lhi = l >> 4;

    bf16x8 B[4][4];
    #pragma unroll
    for (int t = 0; t < 4; t++) {
        int col = t*16 + l15;
        #pragma unroll
        for (int ks = 0; ks < 4; ks++) {
            #pragma unroll
            for (int j = 0; j < 8; j++) {
                int k = ks*32 + lhi*8 + j;
                B[t][ks][j] = f2bf(Wn[k*64 + col]);
            }
        }
    }

    int nb = blockIdx.x * 64;
    int row = nb + 16*w + l15;
    int rowc = row < NN ? row : NN - 1;
    bf16x8 A[4];
    #pragma unroll
    for (int ks = 0; ks < 4; ks++)
        A[ks] = *(const bf16x8*)(out128 + (size_t)rowc*128 + ks*32 + lhi*8);
    #pragma unroll
    for (int t = 0; t < 4; t++) {
        f32x4 acc = {0.f, 0.f, 0.f, 0.f};
        #pragma unroll
        for (int ks = 0; ks < 4; ks++)
            acc = __builtin_amdgcn_mfma_f32_16x16x32_bf16(A[ks], B[t][ks], acc, 0, 0, 0);
        int col = t*16 + l15;
        float bias = bn[col];
        #pragma unroll
        for (int r = 0; r < 4; r++) {
            int node = nb + 16*w + lhi*4 + r;
            if (node < NN) node_out[(size_t)node*64 + col] = acc[r] + bias;
        }
    }
}

// ---------------------------------------------------------------------------
extern "C" void kernel_launch(void* const* d_in, const int* in_sizes, int n_in,
                              void* d_out, int out_size, void* d_ws, size_t ws_size,
                              hipStream_t stream) {
    const float* x         = (const float*)d_in[0];
    const float* edge_attr = (const float*)d_in[1];
    const int*   ei        = (const int*)  d_in[2];
    const float* Wl        = (const float*)d_in[3];
    const float* bl        = (const float*)d_in[4];
    const float* We        = (const float*)d_in[5];
    const float* be        = (const float*)d_in[6];
    const float* W_att     = (const float*)d_in[7];
    const float* b_att     = (const float*)d_in[8];
    const float* att       = (const float*)d_in[9];
    const float* W_nout    = (const float*)d_in[10];
    const float* b_nout    = (const float*)d_in[11];
    const float* W_eout    = (const float*)d_in[12];
    const float* b_eout    = (const float*)d_in[13];

    float* node_out = (float*)d_out;                 // [N,64]
    float* edge_out = node_out + (size_t)NN * 64;    // [E,32]

    char* p = (char*)d_ws;
    u16* XL      = (u16*)p;            p += (size_t)NN * 128 * 2;   // bf16 [N,128]
    u16* UU      = (u16*)p;            p += (size_t)NN * 256 * 2;   // bf16 [N,256]
    u16* out128  = (u16*)p;            p += (size_t)NN * 128 * 2;   // bf16 [N,128]
    float4* aw   = (float4*)p;         p += (size_t)NE * 16;        // CSR {a0,a1,src,_}
    float* WC1   = (float*)p;          p += 128 * 384 * 4;
    float* BC1   = (float*)p;          p += 384 * 4;
    float* WC2   = (float*)p;          p += 64 * 160 * 4;
    float* BC2   = (float*)p;          p += 160 * 4;
    u16*  WC2b   = (u16*)p;            p += 10240 * 2;              // packed B frags
    int*   deg   = (int*)p;            p += NN * 4;
    int*   offs  = (int*)p;            p += (NN + 1) * 4;
    int*   curs  = (int*)p;            p += NN * 4;

    hipMemsetAsync(deg, 0, NN * sizeof(int), stream);

    k_prep<<<(PREP_TOT + 255) / 256, 256, 0, stream>>>(Wl, bl, We, be, W_att, b_att,
                                                       W_eout, b_eout, WC1, BC1, WC2, BC2);
    k_prep2<<<40, 256, 0, stream>>>(WC2, WC2b);
    k_deg<<<(NE + 255) / 256, 256, 0, stream>>>(ei, deg);
    k_scan<<<1, 1024, 0, stream>>>(deg, offs, curs);
    k_node<<<625, 256, 0, stream>>>(x, WC1, BC1, XL, UU);
    k_edge<<<2048, 256, 0, stream>>>(edge_attr, ei, UU, WC2b, BC2, att,
                                     edge_out, curs, aw);
    k_agg<<<2048, 256, 0, stream>>>(XL, aw, offs, out128);
    k_proj<<<(NN + 63) / 64, 256, 0, stream>>>(out128, W_nout, b_nout, node_out);
}